// Round 1
// 997.271 us; speedup vs baseline: 1.0626x; 1.0626x over previous
//
#include <hip/hip_runtime.h>
#include <hip/hip_bf16.h>

#define TOK 16384
#define TAU2 0.001f

typedef __attribute__((ext_vector_type(8))) short short8;
typedef __attribute__((ext_vector_type(4))) float f32x4;

__device__ __forceinline__ unsigned short f32_bf16(float f) {
  __hip_bfloat16 h = __float2bfloat16(f);
  unsigned short u;
  __builtin_memcpy(&u, &h, sizeof(u));
  return u;
}
__device__ __forceinline__ float bf16_f32(unsigned short u) {
  union { unsigned int i; float f; } c; c.i = ((unsigned int)u) << 16; return c.f;
}

__global__ void zero3(int* a, int* c) {
  if (threadIdx.x == 0) { *a = 0; c[0] = 0; c[1] = 0; }
}

__global__ void cvt_kernel(const float* __restrict__ s, unsigned short* __restrict__ d, int n4) {
  int i = blockIdx.x * 256 + threadIdx.x;
  if (i < n4) {
    float4 v = ((const float4*)s)[i];
    union { unsigned short u[4]; uint2 q; } pk;
    pk.u[0] = f32_bf16(v.x); pk.u[1] = f32_bf16(v.y);
    pk.u[2] = f32_bf16(v.z); pk.u[3] = f32_bf16(v.w);
    ((uint2*)d)[i] = pk.q;
  }
}

// split fp32 -> (hi, lo) bf16 pair: hi = bf16(v), lo = bf16(v - f32(hi))
__global__ void cvt_split_kernel(const float* __restrict__ s,
                                 unsigned short* __restrict__ dhi,
                                 unsigned short* __restrict__ dlo, int n4) {
  int i = blockIdx.x * 256 + threadIdx.x;
  if (i < n4) {
    float4 v = ((const float4*)s)[i];
    const float* f = (const float*)&v;
    union { unsigned short u[4]; uint2 q; } hi, lo;
    #pragma unroll
    for (int e = 0; e < 4; e++) {
      unsigned short h = f32_bf16(f[e]);
      hi.u[e] = h;
      lo.u[e] = f32_bf16(f[e] - bf16_f32(h));
    }
    ((uint2*)dhi)[i] = hi.q;
    ((uint2*)dlo)[i] = lo.q;
  }
}

// token compaction by selected branch (runs after sel is final)
__global__ void compact_sel(const int* __restrict__ sel, int* __restrict__ idx1,
                            int* __restrict__ idx2, int* __restrict__ cnt) {
  int t = blockIdx.x * 256 + threadIdx.x;
  int s = sel[t];
  if (s == 1) idx1[atomicAdd(&cnt[0], 1)] = t;
  else if (s == 2) idx2[atomicAdd(&cnt[1], 1)] = t;
}

// pad index lists to a multiple of 128 with -1 sentinels; publish padded counts
__global__ void pad_idx(int* __restrict__ idx1, int* __restrict__ idx2,
                        const int* __restrict__ cnt, int* __restrict__ mc) {
  const int tid = threadIdx.x;
  const int n1 = cnt[0], n2 = cnt[1];
  const int p1 = (n1 + 127) & ~(int)127, p2 = (n2 + 127) & ~(int)127;
  if (tid < p1 - n1) idx1[n1 + tid] = -1;
  if (tid < p2 - n2) idx2[n2 + tid] = -1;
  if (tid == 0) { mc[0] = p1; mc[1] = p2; }
}

// C[M,N] = A[M,K] * Bw[N,K]^T  (+bias, epilogue variants)
// AMODE: 0 = fp32 A (convert on the fly), 2 = bf16 A direct,
//        3 = fp32 A scaled per row-half, SPLIT hi/lo; B split (Bw=hi, Bw2=lo);
//            3 MFMAs per fragment pair (near-fp32 product accuracy)
// EPI:   0 = bias -> bf16 store, 1 = relu(bias) -> bf16 store,
//        3 = relu(bias) -> fp32 store,
//        4 = bias -> fp32 scatter store to out row idx[row] (skip idx<0)
// AG:    1 = gather A rows through idx (sentinel -1 clamps to row 0)
// mcp:   if non-null, active row count (padded to 128); blocks past it exit.
template<int AMODE, int EPI, int AG>
__global__ __launch_bounds__(256, 2)
void gemm_tile(const void* __restrict__ Av,
               const unsigned short* __restrict__ Bw,
               const unsigned short* __restrict__ Bw2,
               const float* __restrict__ bias,
               void* __restrict__ Outv,
               const float* __restrict__ scA, const float* __restrict__ scB,
               const int* __restrict__ idx, const int* __restrict__ mcp,
               int M, int N, int K) {
  __shared__ __align__(16) unsigned short As[(AMODE == 3 ? 2 : 1) * 128 * 32];
  __shared__ __align__(16) unsigned short Bs[(AMODE == 3 ? 2 : 1) * 128 * 32];
  const int LO = 128 * 32;  // offset of lo-half when AMODE==3
  const int tid = threadIdx.x;
  const int m0 = blockIdx.y * 128, n0 = blockIdx.x * 128;
  if (mcp && m0 >= *mcp) return;
  const int lane = tid & 63, wave = tid >> 6;
  const int wm = wave >> 1, wn = wave & 1;
  const int quad = lane >> 4, lr = lane & 15;
  const int srow = tid >> 1, scol = (tid & 1) * 16;

  // hoist A/B row bases (incl. gather indirection) out of the K loop
  size_t aRowOff;
  {
    int ar = m0 + srow;
    if (AG) { int t = idx[ar]; ar = (t < 0) ? 0 : t; }
    aRowOff = (size_t)ar * K;
  }
  const unsigned short* Brow = Bw + (size_t)(n0 + srow) * K;
  const unsigned short* Brow2 = (AMODE == 3) ? (Bw2 + (size_t)(n0 + srow) * K) : nullptr;

  f32x4 acc[4][4] = {};

  for (int k0 = 0; k0 < K; k0 += 32) {
    // ---- stage A tile [128][32]
    if (AMODE == 2) {
      const unsigned short* A = (const unsigned short*)Av;
      const uint4* src = (const uint4*)(A + aRowOff + k0 + scol);
      uint4* dst = (uint4*)(As + srow * 32 + scol);
      dst[0] = src[0]; dst[1] = src[1];
    } else {
      const float* A = (const float*)Av;
      const float4* src = (const float4*)(A + aRowOff + k0 + scol);
      float4 f[4];
      f[0] = src[0]; f[1] = src[1]; f[2] = src[2]; f[3] = src[3];
      float s = 1.0f;
      if (AMODE == 3) {
        int tk = m0 + srow;
        s = ((k0 + scol) * 2 < K) ? scA[tk] : scB[tk];
      }
      union { unsigned short u[16]; uint4 q[2]; } hi;
      union { unsigned short u[16]; uint4 q[2]; } lo;
      const float* ff = (const float*)f;
      #pragma unroll
      for (int e = 0; e < 16; e++) {
        float fv = ff[e];
        if (AMODE == 3) fv *= s;
        unsigned short hb = f32_bf16(fv);
        hi.u[e] = hb;
        if (AMODE == 3) lo.u[e] = f32_bf16(fv - bf16_f32(hb));
      }
      uint4* dst = (uint4*)(As + srow * 32 + scol);
      dst[0] = hi.q[0]; dst[1] = hi.q[1];
      if (AMODE == 3) {
        uint4* dst2 = (uint4*)(As + LO + srow * 32 + scol);
        dst2[0] = lo.q[0]; dst2[1] = lo.q[1];
      }
    }
    // ---- stage B tile [128][32] (bf16 weights, row-major [N,K])
    {
      const uint4* src = (const uint4*)(Brow + k0 + scol);
      uint4* dst = (uint4*)(Bs + srow * 32 + scol);
      dst[0] = src[0]; dst[1] = src[1];
      if (AMODE == 3) {
        const uint4* src2 = (const uint4*)(Brow2 + k0 + scol);
        uint4* dst2 = (uint4*)(Bs + LO + srow * 32 + scol);
        dst2[0] = src2[0]; dst2[1] = src2[1];
      }
    }
    __syncthreads();
    short8 af[4], bfr[4];
    #pragma unroll
    for (int i = 0; i < 4; i++)
      af[i] = *(const short8*)(As + (wm * 64 + i * 16 + lr) * 32 + quad * 8);
    #pragma unroll
    for (int j = 0; j < 4; j++)
      bfr[j] = *(const short8*)(Bs + (wn * 64 + j * 16 + lr) * 32 + quad * 8);
    if (AMODE == 3) {
      short8 af2[4], bf2[4];
      #pragma unroll
      for (int i = 0; i < 4; i++)
        af2[i] = *(const short8*)(As + LO + (wm * 64 + i * 16 + lr) * 32 + quad * 8);
      #pragma unroll
      for (int j = 0; j < 4; j++)
        bf2[j] = *(const short8*)(Bs + LO + (wn * 64 + j * 16 + lr) * 32 + quad * 8);
      #pragma unroll
      for (int i = 0; i < 4; i++)
        #pragma unroll
        for (int j = 0; j < 4; j++) {
          acc[i][j] = __builtin_amdgcn_mfma_f32_16x16x32_bf16(af[i], bfr[j], acc[i][j], 0, 0, 0);
          acc[i][j] = __builtin_amdgcn_mfma_f32_16x16x32_bf16(af[i], bf2[j], acc[i][j], 0, 0, 0);
          acc[i][j] = __builtin_amdgcn_mfma_f32_16x16x32_bf16(af2[i], bfr[j], acc[i][j], 0, 0, 0);
        }
    } else {
      #pragma unroll
      for (int i = 0; i < 4; i++)
        #pragma unroll
        for (int j = 0; j < 4; j++)
          acc[i][j] = __builtin_amdgcn_mfma_f32_16x16x32_bf16(af[i], bfr[j], acc[i][j], 0, 0, 0);
    }
    __syncthreads();
  }

  // ---- epilogue: C/D layout col=lane&15 (n), row=quad*4+reg (m)
  #pragma unroll
  for (int i = 0; i < 4; i++) {
    const int rbase = m0 + wm * 64 + i * 16 + quad * 4;
    #pragma unroll
    for (int j = 0; j < 4; j++) {
      const int col = n0 + wn * 64 + j * 16 + lr;
      const float bv = bias[col];
      #pragma unroll
      for (int r = 0; r < 4; r++) {
        const int row = rbase + r;
        float v = acc[i][j][r] + bv;
        if (EPI == 0) {
          ((unsigned short*)Outv)[(size_t)row * N + col] = f32_bf16(v);
        } else if (EPI == 1) {
          ((unsigned short*)Outv)[(size_t)row * N + col] = f32_bf16(fmaxf(v, 0.0f));
        } else if (EPI == 3) {
          ((float*)Outv)[(size_t)row * N + col] = fmaxf(v, 0.0f);
        } else {  // EPI == 4: scatter through idx
          const int t = idx[row];
          if (t >= 0) ((float*)Outv)[(size_t)t * N + col] = v;
        }
      }
    }
  }
}

// logits from fp32 hid (split-GEMM output), argmax + tight margin flagging.
// One wave per token.
__global__ __launch_bounds__(256)
void selector_logits_f32(const float* __restrict__ hidf,
                         const float* __restrict__ W2, const float* __restrict__ b2,
                         int* __restrict__ sel, int* __restrict__ risky,
                         int* __restrict__ riskyCount) {
  const int wave = threadIdx.x >> 6, lane = threadIdx.x & 63;
  const int token = blockIdx.x * 4 + wave;
  const float* hs = hidf + (size_t)token * 512 + lane * 8;
  float4 h0 = *(const float4*)hs, h1 = *(const float4*)(hs + 4);
  float p[3];
  #pragma unroll
  for (int c = 0; c < 3; c++) {
    const float* w = W2 + c * 512 + lane * 8;
    float4 w0 = *(const float4*)w, w1 = *(const float4*)(w + 4);
    p[c] = h0.x*w0.x + h0.y*w0.y + h0.z*w0.z + h0.w*w0.w
         + h1.x*w1.x + h1.y*w1.y + h1.z*w1.z + h1.w*w1.w;
  }
  #pragma unroll
  for (int off = 32; off >= 1; off >>= 1) {
    #pragma unroll
    for (int c = 0; c < 3; c++) p[c] += __shfl_xor(p[c], off, 64);
  }
  if (lane == 0) {
    float l0 = p[0] + b2[0], l1 = p[1] + b2[1], l2 = p[2] + b2[2];
    int arg = 0; float best = l0;
    if (l1 > best) { best = l1; arg = 1; }
    if (l2 > best) { best = l2; arg = 2; }
    float second;
    if (arg == 0) second = fmaxf(l1, l2);
    else if (arg == 1) second = fmaxf(l0, l2);
    else second = fmaxf(l0, l1);
    sel[token] = arg;
    if (best - second < TAU2) {
      int idx = atomicAdd(riskyCount, 1);
      risky[idx] = token;
    }
  }
}

// exact fp32 selector recompute for ultra-near-tie tokens (~100 expected).
__global__ __launch_bounds__(256)
void recheck_exact(const float* __restrict__ h, const float* __restrict__ freq,
                   const float* __restrict__ imp,
                   const float* __restrict__ W1, const float* __restrict__ b1,
                   const float* __restrict__ W2, const float* __restrict__ b2,
                   const int* __restrict__ risky, const int* __restrict__ riskyCount,
                   int* __restrict__ sel) {
  __shared__ float h_sh[2048];
  __shared__ float hid_sh[512];
  const int n = *riskyCount;
  const int tid = threadIdx.x;
  for (int ri = blockIdx.x; ri < n; ri += gridDim.x) {
    const int token = risky[ri];
    {
      const float s = (tid < 128) ? freq[token] : imp[token];
      const float4* src = (const float4*)(h + (size_t)token * 2048) + tid * 2;
      float4 v0 = src[0], v1 = src[1];
      v0.x *= s; v0.y *= s; v0.z *= s; v0.w *= s;
      v1.x *= s; v1.y *= s; v1.z *= s; v1.w *= s;
      ((float4*)h_sh)[tid * 2] = v0;
      ((float4*)h_sh)[tid * 2 + 1] = v1;
    }
    __syncthreads();
    #pragma unroll
    for (int half = 0; half < 2; half++) {
      const int o = tid + half * 256;
      const float* wrow = W1 + (size_t)o * 2048;
      float a0 = 0.f, a1 = 0.f, a2 = 0.f, a3 = 0.f;
      for (int k = 0; k < 2048; k += 16) {
        float4 w0 = *(const float4*)(wrow + k);
        float4 w1v = *(const float4*)(wrow + k + 4);
        float4 w2v = *(const float4*)(wrow + k + 8);
        float4 w3v = *(const float4*)(wrow + k + 12);
        float4 x0 = *(const float4*)(h_sh + k);
        float4 x1 = *(const float4*)(h_sh + k + 4);
        float4 x2 = *(const float4*)(h_sh + k + 8);
        float4 x3 = *(const float4*)(h_sh + k + 12);
        a0 += w0.x*x0.x + w0.y*x0.y + w0.z*x0.z + w0.w*x0.w;
        a1 += w1v.x*x1.x + w1v.y*x1.y + w1v.z*x1.z + w1v.w*x1.w;
        a2 += w2v.x*x2.x + w2v.y*x2.y + w2v.z*x2.z + w2v.w*x2.w;
        a3 += w3v.x*x3.x + w3v.y*x3.y + w3v.z*x3.z + w3v.w*x3.w;
      }
      hid_sh[o] = fmaxf((a0 + a1) + (a2 + a3) + b1[o], 0.0f);
    }
    __syncthreads();
    if (tid < 64) {
      const int lane = tid;
      const float* hs = &hid_sh[lane * 8];
      float l[3];
      #pragma unroll
      for (int c = 0; c < 3; c++) {
        const float* w = W2 + c * 512 + lane * 8;
        float s = 0.0f;
        #pragma unroll
        for (int e = 0; e < 8; e++) s += hs[e] * w[e];
        l[c] = s;
      }
      #pragma unroll
      for (int off = 32; off >= 1; off >>= 1)
        #pragma unroll
        for (int c = 0; c < 3; c++) l[c] += __shfl_xor(l[c], off, 64);
      if (lane == 0) {
        float l0 = l[0] + b2[0], l1 = l[1] + b2[1], l2 = l[2] + b2[2];
        int arg = 0; float best = l0;
        if (l1 > best) { best = l1; arg = 1; }
        if (l2 > best) { arg = 2; }
        sel[token] = arg;
      }
    }
    __syncthreads();
  }
}

__global__ __launch_bounds__(256)
void copy_sel0(const float* __restrict__ h, const int* __restrict__ sel,
               float* __restrict__ out) {
  const int token = blockIdx.x;
  if (sel[token] != 0) return;
  const float4* src = (const float4*)(h + (size_t)token * 2048);
  float4* dst = (float4*)(out + (size_t)token * 2048);
  dst[threadIdx.x] = src[threadIdx.x];
  dst[threadIdx.x + 256] = src[threadIdx.x + 256];
}

extern "C" void kernel_launch(void* const* d_in, const int* in_sizes, int n_in,
                              void* d_out, int out_size, void* d_ws, size_t ws_size,
                              hipStream_t stream) {
  const float* h        = (const float*)d_in[0];
  const float* freq     = (const float*)d_in[1];
  const float* imp      = (const float*)d_in[2];
  const float* comp1W   = (const float*)d_in[3];
  const float* comp1b   = (const float*)d_in[4];
  const float* adapt1W  = (const float*)d_in[5];
  const float* adapt1b  = (const float*)d_in[6];
  const float* decomp1W = (const float*)d_in[7];
  const float* decomp1b = (const float*)d_in[8];
  const float* comp2W   = (const float*)d_in[9];
  const float* comp2b   = (const float*)d_in[10];
  const float* adapt2W  = (const float*)d_in[11];
  const float* adapt2b  = (const float*)d_in[12];
  const float* decomp2W = (const float*)d_in[13];
  const float* decomp2b = (const float*)d_in[14];
  const float* sel1W    = (const float*)d_in[15];
  const float* sel1b    = (const float*)d_in[16];
  const float* sel2W    = (const float*)d_in[17];
  const float* sel2b    = (const float*)d_in[18];
  float* out = (float*)d_out;

  char* ws = (char*)d_ws;
  size_t off = 0;
  auto alloc = [&](size_t bytes) -> void* {
    void* p = ws + off; off += (bytes + 255) & ~(size_t)255; return p;
  };
  unsigned short* wb_comp1   = (unsigned short*)alloc((size_t)1024 * 2048 * 2);
  unsigned short* wb_adapt1  = (unsigned short*)alloc((size_t)1024 * 1024 * 2);
  unsigned short* wb_decomp1 = (unsigned short*)alloc((size_t)2048 * 1024 * 2);
  unsigned short* wb_comp2   = (unsigned short*)alloc((size_t)512 * 2048 * 2);
  unsigned short* wb_adapt2  = (unsigned short*)alloc((size_t)512 * 512 * 2);
  unsigned short* wb_decomp2 = (unsigned short*)alloc((size_t)2048 * 512 * 2);
  unsigned short* w1hi       = (unsigned short*)alloc((size_t)512 * 2048 * 2);
  unsigned short* w1lo       = (unsigned short*)alloc((size_t)512 * 2048 * 2);
  float*          hidf       = (float*)alloc((size_t)TOK * 512 * 4);
  unsigned short* c1         = (unsigned short*)alloc((size_t)TOK * 1024 * 2);
  unsigned short* a1         = (unsigned short*)alloc((size_t)TOK * 1024 * 2);
  int* sel        = (int*)alloc((size_t)TOK * 4);
  int* risky      = (int*)alloc((size_t)TOK * 4);
  int* riskyCount = (int*)alloc(256);
  int* idx1       = (int*)alloc((size_t)TOK * 4);
  int* idx2       = (int*)alloc((size_t)TOK * 4);
  int* cnt        = (int*)alloc(256);   // [0]=n1, [1]=n2
  int* mc         = (int*)alloc(256);   // [0]=p1, [1]=p2 (padded to 128)
  unsigned short* c2 = c1;   // branch 2 runs after branch 1 finished
  unsigned short* a2 = a1;

  zero3<<<1, 64, 0, stream>>>(riskyCount, cnt);

  auto cvt = [&](const float* s, unsigned short* d, int n) {
    cvt_kernel<<<(n / 4 + 255) / 256, 256, 0, stream>>>(s, d, n / 4);
  };
  cvt(comp1W,   wb_comp1,   1024 * 2048);
  cvt(adapt1W,  wb_adapt1,  1024 * 1024);
  cvt(decomp1W, wb_decomp1, 2048 * 1024);
  cvt(comp2W,   wb_comp2,   512 * 2048);
  cvt(adapt2W,  wb_adapt2,  512 * 512);
  cvt(decomp2W, wb_decomp2, 2048 * 512);
  cvt_split_kernel<<<(512 * 2048 / 4 + 255) / 256, 256, 0, stream>>>(
      sel1W, w1hi, w1lo, 512 * 2048 / 4);

  // selector: hid = relu(combined @ sel1W^T + b) in split-bf16 (near-fp32), fp32 store
  gemm_tile<3, 3, 0><<<dim3(512 / 128, TOK / 128), 256, 0, stream>>>(
      h, w1hi, w1lo, sel1b, hidf, freq, imp, nullptr, nullptr, TOK, 512, 2048);
  selector_logits_f32<<<TOK / 4, 256, 0, stream>>>(hidf, sel2W, sel2b, sel, risky, riskyCount);
  recheck_exact<<<256, 256, 0, stream>>>(h, freq, imp, sel1W, sel1b, sel2W, sel2b,
                                         risky, riskyCount, sel);

  // token compaction: branch GEMMs only run over their selected tokens
  compact_sel<<<TOK / 256, 256, 0, stream>>>(sel, idx1, idx2, cnt);
  pad_idx<<<1, 256, 0, stream>>>(idx1, idx2, cnt, mc);

  // branch 1: H -> H/2 -> H/2 -> H on compacted token set (gather A, scatter out)
  gemm_tile<0, 0, 1><<<dim3(1024 / 128, TOK / 128), 256, 0, stream>>>(
      h, wb_comp1, nullptr, comp1b, c1, nullptr, nullptr, idx1, mc + 0, TOK, 1024, 2048);
  gemm_tile<2, 0, 0><<<dim3(1024 / 128, TOK / 128), 256, 0, stream>>>(
      c1, wb_adapt1, nullptr, adapt1b, a1, nullptr, nullptr, nullptr, mc + 0, TOK, 1024, 1024);
  gemm_tile<2, 4, 0><<<dim3(2048 / 128, TOK / 128), 256, 0, stream>>>(
      a1, wb_decomp1, nullptr, decomp1b, out, nullptr, nullptr, idx1, mc + 0, TOK, 2048, 1024);

  // branch 2: H -> H/4 -> H/4 -> H on compacted token set
  gemm_tile<0, 0, 1><<<dim3(512 / 128, TOK / 128), 256, 0, stream>>>(
      h, wb_comp2, nullptr, comp2b, c2, nullptr, nullptr, idx2, mc + 1, TOK, 512, 2048);
  gemm_tile<2, 0, 0><<<dim3(512 / 128, TOK / 128), 256, 0, stream>>>(
      c2, wb_adapt2, nullptr, adapt2b, a2, nullptr, nullptr, nullptr, mc + 1, TOK, 512, 512);
  gemm_tile<2, 4, 0><<<dim3(2048 / 128, TOK / 128), 256, 0, stream>>>(
      a2, wb_decomp2, nullptr, decomp2b, out, nullptr, nullptr, idx2, mc + 1, TOK, 2048, 512);

  // sel==0 tokens: exact fp32 passthrough of h
  copy_sel0<<<TOK, 256, 0, stream>>>(h, sel, out);
}

// Round 3
// 978.369 us; speedup vs baseline: 1.0831x; 1.0193x over previous
//
#include <hip/hip_runtime.h>
#include <hip/hip_bf16.h>

#define TOK 16384
#define TAU2 0.001f

typedef __attribute__((ext_vector_type(8))) short short8;
typedef __attribute__((ext_vector_type(4))) float f32x4;

__device__ __forceinline__ unsigned short f32_bf16(float f) {
  __hip_bfloat16 h = __float2bfloat16(f);
  unsigned short u;
  __builtin_memcpy(&u, &h, sizeof(u));
  return u;
}
__device__ __forceinline__ float bf16_f32(unsigned short u) {
  union { unsigned int i; float f; } c; c.i = ((unsigned int)u) << 16; return c.f;
}

// async global->LDS, 16B per lane; LDS dest linear in lane order (HW writes
// readfirstlane(base) + lane*16; our per-lane address equals exactly that).
__device__ __forceinline__ void gll16(const unsigned short* g, unsigned short* l) {
  __builtin_amdgcn_global_load_lds(
      (const __attribute__((address_space(1))) unsigned int*)g,
      (__attribute__((address_space(3))) unsigned int*)l, 16, 0, 0);
}

__global__ void zero3(int* a, int* c) {
  if (threadIdx.x == 0) { *a = 0; c[0] = 0; c[1] = 0; }
}

__global__ void cvt_kernel(const float* __restrict__ s, unsigned short* __restrict__ d, int n4) {
  int i = blockIdx.x * 256 + threadIdx.x;
  if (i < n4) {
    float4 v = ((const float4*)s)[i];
    union { unsigned short u[4]; uint2 q; } pk;
    pk.u[0] = f32_bf16(v.x); pk.u[1] = f32_bf16(v.y);
    pk.u[2] = f32_bf16(v.z); pk.u[3] = f32_bf16(v.w);
    ((uint2*)d)[i] = pk.q;
  }
}

// split fp32 -> (hi, lo) bf16 pair: hi = bf16(v), lo = bf16(v - f32(hi))
__global__ void cvt_split_kernel(const float* __restrict__ s,
                                 unsigned short* __restrict__ dhi,
                                 unsigned short* __restrict__ dlo, int n4) {
  int i = blockIdx.x * 256 + threadIdx.x;
  if (i < n4) {
    float4 v = ((const float4*)s)[i];
    const float* f = (const float*)&v;
    union { unsigned short u[4]; uint2 q; } hi, lo;
    #pragma unroll
    for (int e = 0; e < 4; e++) {
      unsigned short h = f32_bf16(f[e]);
      hi.u[e] = h;
      lo.u[e] = f32_bf16(f[e] - bf16_f32(h));
    }
    ((uint2*)dhi)[i] = hi.q;
    ((uint2*)dlo)[i] = lo.q;
  }
}

// token compaction by selected branch (runs after sel is final)
__global__ void compact_sel(const int* __restrict__ sel, int* __restrict__ idx1,
                            int* __restrict__ idx2, int* __restrict__ cnt) {
  int t = blockIdx.x * 256 + threadIdx.x;
  int s = sel[t];
  if (s == 1) idx1[atomicAdd(&cnt[0], 1)] = t;
  else if (s == 2) idx2[atomicAdd(&cnt[1], 1)] = t;
}

// pad index lists to a multiple of 128 with -1 sentinels; publish padded counts
__global__ void pad_idx(int* __restrict__ idx1, int* __restrict__ idx2,
                        const int* __restrict__ cnt, int* __restrict__ mc) {
  const int tid = threadIdx.x;
  const int n1 = cnt[0], n2 = cnt[1];
  const int p1 = (n1 + 127) & ~(int)127, p2 = (n2 + 127) & ~(int)127;
  if (tid < p1 - n1) idx1[n1 + tid] = -1;
  if (tid < p2 - n2) idx2[n2 + tid] = -1;
  if (tid == 0) { mc[0] = p1; mc[1] = p2; }
}

// ---------------------------------------------------------------------------
// bf16 GEMM, 128x128 tile, BK=64, global_load_lds staging (16B/lane), LDS
// double-buffer with one barrier per k-tile, XOR-swizzled LDS (write-side via
// pre-swizzled global source chunk, read-side via matching XOR) ->
// conflict-free ds_read_b128.
// C[M,N] = A[M,K] * Bw[N,K]^T + bias
// EPI: 0 = bf16 store, 4 = fp32 scatter store to out row idx[row] (skip idx<0)
// AG:  1 = gather A rows through idx (sentinel -1 clamps to row 0)
// mcp: active row count (padded to 128); blocks past it exit.
// ---------------------------------------------------------------------------
template<int EPI, int AG>
__global__ __launch_bounds__(256, 2)
void gemm_bf16(const unsigned short* __restrict__ A,
               const unsigned short* __restrict__ Bw,
               const float* __restrict__ bias,
               void* __restrict__ Outv,
               const int* __restrict__ idx, const int* __restrict__ mcp,
               int N, int K) {
  __shared__ __align__(16) unsigned short As[2][128 * 64];
  __shared__ __align__(16) unsigned short Bs[2][128 * 64];
  const int tid = threadIdx.x;
  const int m0 = blockIdx.y * 128, n0 = blockIdx.x * 128;
  if (mcp && m0 >= *mcp) return;
  const int lane = tid & 63, wave = tid >> 6;
  const int wm = wave >> 1, wn = wave & 1;
  const int quad = lane >> 4, lr = lane & 15;

  // staging geometry: call r covers tile row (r*32 + wave*8 + lane>>3).
  // LDS dest is linear (lane&7 chunk); content must be global chunk
  // (lane&7) ^ (row&7); row&7 == lane>>3 here.
  const int srow = wave * 8 + (lane >> 3);        // 0..31
  const int schunk = (lane & 7) ^ (lane >> 3);    // pre-swizzled source chunk
  unsigned int aoff[4], boff[4];
  #pragma unroll
  for (int r = 0; r < 4; r++) {
    int row = r * 32 + srow;
    int gr = m0 + row;
    if (AG) { int t = idx[gr]; gr = (t < 0) ? 0 : t; }
    aoff[r] = (unsigned int)gr * (unsigned int)K + (unsigned int)(schunk * 8);
    boff[r] = (unsigned int)(n0 + row) * (unsigned int)K + (unsigned int)(schunk * 8);
  }
  // shorts; equals wave-base + lane*8 (16B per lane, linear)
  const int lds_dst = (lane & 7) * 8 + (lane >> 3) * 64 + wave * 512;

  f32x4 acc[4][4] = {};
  const int nk = K >> 6;

  // prologue: stage tile 0
  #pragma unroll
  for (int r = 0; r < 4; r++) {
    gll16(A + aoff[r], &As[0][r * 2048 + lds_dst]);
    gll16(Bw + boff[r], &Bs[0][r * 2048 + lds_dst]);
  }
  __syncthreads();

  int cur = 0;
  for (int t = 0; t < nk; t++) {
    if (t + 1 < nk) {
      const int k0 = (t + 1) << 6;
      #pragma unroll
      for (int r = 0; r < 4; r++) {
        gll16(A + aoff[r] + k0, &As[cur ^ 1][r * 2048 + lds_dst]);
        gll16(Bw + boff[r] + k0, &Bs[cur ^ 1][r * 2048 + lds_dst]);
      }
    }
    #pragma unroll
    for (int kk = 0; kk < 2; kk++) {
      short8 af[4], bfr[4];
      #pragma unroll
      for (int i = 0; i < 4; i++) {
        const int row = wm * 64 + i * 16 + lr;
        const int c = kk * 4 + quad;
        af[i] = *(const short8*)(&As[cur][row * 64 + ((c ^ (row & 7)) << 3)]);
      }
      #pragma unroll
      for (int j = 0; j < 4; j++) {
        const int row = wn * 64 + j * 16 + lr;
        const int c = kk * 4 + quad;
        bfr[j] = *(const short8*)(&Bs[cur][row * 64 + ((c ^ (row & 7)) << 3)]);
      }
      #pragma unroll
      for (int i = 0; i < 4; i++)
        #pragma unroll
        for (int j = 0; j < 4; j++)
          acc[i][j] = __builtin_amdgcn_mfma_f32_16x16x32_bf16(af[i], bfr[j], acc[i][j], 0, 0, 0);
    }
    __syncthreads();  // drains vmcnt (next tile landed) + all waves done with cur
    cur ^= 1;
  }

  // epilogue: C/D layout col=lane&15 (n), row=quad*4+reg (m)
  #pragma unroll
  for (int i = 0; i < 4; i++) {
    const int rbase = m0 + wm * 64 + i * 16 + quad * 4;
    #pragma unroll
    for (int j = 0; j < 4; j++) {
      const int col = n0 + wn * 64 + j * 16 + lr;
      const float bv = bias[col];
      #pragma unroll
      for (int r = 0; r < 4; r++) {
        const int row = rbase + r;
        float v = acc[i][j][r] + bv;
        if (EPI == 0) {
          ((unsigned short*)Outv)[(size_t)row * N + col] = f32_bf16(v);
        } else {  // EPI == 4
          const int tk = idx[row];
          if (tk >= 0) ((float*)Outv)[(size_t)tk * N + col] = v;
        }
      }
    }
  }
}

// ---------------------------------------------------------------------------
// selector GEMM (unchanged, proven): fp32 A scaled per row-half, split hi/lo
// bf16; 3 MFMAs per fragment pair; relu + fp32 store.
// ---------------------------------------------------------------------------
__global__ __launch_bounds__(256, 2)
void gemm_sel(const float* __restrict__ Af,
              const unsigned short* __restrict__ Bw,
              const unsigned short* __restrict__ Bw2,
              const float* __restrict__ bias,
              float* __restrict__ Out,
              const float* __restrict__ scA, const float* __restrict__ scB,
              int N, int K) {
  __shared__ __align__(16) unsigned short As[2 * 128 * 32];
  __shared__ __align__(16) unsigned short Bs[2 * 128 * 32];
  const int LO = 128 * 32;
  const int tid = threadIdx.x;
  const int m0 = blockIdx.y * 128, n0 = blockIdx.x * 128;
  const int lane = tid & 63, wave = tid >> 6;
  const int wm = wave >> 1, wn = wave & 1;
  const int quad = lane >> 4, lr = lane & 15;
  const int srow = tid >> 1, scol = (tid & 1) * 16;

  const size_t aRowOff = (size_t)(m0 + srow) * K;
  const unsigned short* Brow = Bw + (size_t)(n0 + srow) * K;
  const unsigned short* Brow2 = Bw2 + (size_t)(n0 + srow) * K;

  f32x4 acc[4][4] = {};

  for (int k0 = 0; k0 < K; k0 += 32) {
    {
      const float4* src = (const float4*)(Af + aRowOff + k0 + scol);
      float4 f[4];
      f[0] = src[0]; f[1] = src[1]; f[2] = src[2]; f[3] = src[3];
      const int tk = m0 + srow;
      const float s = ((k0 + scol) * 2 < K) ? scA[tk] : scB[tk];
      union { unsigned short u[16]; uint4 q[2]; } hi;
      union { unsigned short u[16]; uint4 q[2]; } lo;
      const float* ff = (const float*)f;
      #pragma unroll
      for (int e = 0; e < 16; e++) {
        float fv = ff[e] * s;
        unsigned short hb = f32_bf16(fv);
        hi.u[e] = hb;
        lo.u[e] = f32_bf16(fv - bf16_f32(hb));
      }
      uint4* dst = (uint4*)(As + srow * 32 + scol);
      dst[0] = hi.q[0]; dst[1] = hi.q[1];
      uint4* dst2 = (uint4*)(As + LO + srow * 32 + scol);
      dst2[0] = lo.q[0]; dst2[1] = lo.q[1];
    }
    {
      const uint4* src = (const uint4*)(Brow + k0 + scol);
      uint4* dst = (uint4*)(Bs + srow * 32 + scol);
      dst[0] = src[0]; dst[1] = src[1];
      const uint4* src2 = (const uint4*)(Brow2 + k0 + scol);
      uint4* dst2 = (uint4*)(Bs + LO + srow * 32 + scol);
      dst2[0] = src2[0]; dst2[1] = src2[1];
    }
    __syncthreads();
    short8 af[4], bfr[4], af2[4], bf2[4];
    #pragma unroll
    for (int i = 0; i < 4; i++) {
      af[i]  = *(const short8*)(As + (wm * 64 + i * 16 + lr) * 32 + quad * 8);
      af2[i] = *(const short8*)(As + LO + (wm * 64 + i * 16 + lr) * 32 + quad * 8);
    }
    #pragma unroll
    for (int j = 0; j < 4; j++) {
      bfr[j] = *(const short8*)(Bs + (wn * 64 + j * 16 + lr) * 32 + quad * 8);
      bf2[j] = *(const short8*)(Bs + LO + (wn * 64 + j * 16 + lr) * 32 + quad * 8);
    }
    #pragma unroll
    for (int i = 0; i < 4; i++)
      #pragma unroll
      for (int j = 0; j < 4; j++) {
        acc[i][j] = __builtin_amdgcn_mfma_f32_16x16x32_bf16(af[i], bfr[j], acc[i][j], 0, 0, 0);
        acc[i][j] = __builtin_amdgcn_mfma_f32_16x16x32_bf16(af[i], bf2[j], acc[i][j], 0, 0, 0);
        acc[i][j] = __builtin_amdgcn_mfma_f32_16x16x32_bf16(af2[i], bfr[j], acc[i][j], 0, 0, 0);
      }
    __syncthreads();
  }

  #pragma unroll
  for (int i = 0; i < 4; i++) {
    const int rbase = m0 + wm * 64 + i * 16 + quad * 4;
    #pragma unroll
    for (int j = 0; j < 4; j++) {
      const int col = n0 + wn * 64 + j * 16 + lr;
      const float bv = bias[col];
      #pragma unroll
      for (int r = 0; r < 4; r++) {
        const int row = rbase + r;
        float v = acc[i][j][r] + bv;
        Out[(size_t)row * N + col] = fmaxf(v, 0.0f);
      }
    }
  }
}

// logits from fp32 hid, argmax + tight margin flagging. One wave per token.
__global__ __launch_bounds__(256)
void selector_logits_f32(const float* __restrict__ hidf,
                         const float* __restrict__ W2, const float* __restrict__ b2,
                         int* __restrict__ sel, int* __restrict__ risky,
                         int* __restrict__ riskyCount) {
  const int wave = threadIdx.x >> 6, lane = threadIdx.x & 63;
  const int token = blockIdx.x * 4 + wave;
  const float* hs = hidf + (size_t)token * 512 + lane * 8;
  float4 h0 = *(const float4*)hs, h1 = *(const float4*)(hs + 4);
  float p[3];
  #pragma unroll
  for (int c = 0; c < 3; c++) {
    const float* w = W2 + c * 512 + lane * 8;
    float4 w0 = *(const float4*)w, w1 = *(const float4*)(w + 4);
    p[c] = h0.x*w0.x + h0.y*w0.y + h0.z*w0.z + h0.w*w0.w
         + h1.x*w1.x + h1.y*w1.y + h1.z*w1.z + h1.w*w1.w;
  }
  #pragma unroll
  for (int off = 32; off >= 1; off >>= 1) {
    #pragma unroll
    for (int c = 0; c < 3; c++) p[c] += __shfl_xor(p[c], off, 64);
  }
  if (lane == 0) {
    float l0 = p[0] + b2[0], l1 = p[1] + b2[1], l2 = p[2] + b2[2];
    int arg = 0; float best = l0;
    if (l1 > best) { best = l1; arg = 1; }
    if (l2 > best) { best = l2; arg = 2; }
    float second;
    if (arg == 0) second = fmaxf(l1, l2);
    else if (arg == 1) second = fmaxf(l0, l2);
    else second = fmaxf(l0, l1);
    sel[token] = arg;
    if (best - second < TAU2) {
      int idx = atomicAdd(riskyCount, 1);
      risky[idx] = token;
    }
  }
}

// exact fp32 selector recompute for ultra-near-tie tokens (~100 expected).
__global__ __launch_bounds__(256)
void recheck_exact(const float* __restrict__ h, const float* __restrict__ freq,
                   const float* __restrict__ imp,
                   const float* __restrict__ W1, const float* __restrict__ b1,
                   const float* __restrict__ W2, const float* __restrict__ b2,
                   const int* __restrict__ risky, const int* __restrict__ riskyCount,
                   int* __restrict__ sel) {
  __shared__ float h_sh[2048];
  __shared__ float hid_sh[512];
  const int n = *riskyCount;
  const int tid = threadIdx.x;
  for (int ri = blockIdx.x; ri < n; ri += gridDim.x) {
    const int token = risky[ri];
    {
      const float s = (tid < 128) ? freq[token] : imp[token];
      const float4* src = (const float4*)(h + (size_t)token * 2048) + tid * 2;
      float4 v0 = src[0], v1 = src[1];
      v0.x *= s; v0.y *= s; v0.z *= s; v0.w *= s;
      v1.x *= s; v1.y *= s; v1.z *= s; v1.w *= s;
      ((float4*)h_sh)[tid * 2] = v0;
      ((float4*)h_sh)[tid * 2 + 1] = v1;
    }
    __syncthreads();
    #pragma unroll
    for (int half = 0; half < 2; half++) {
      const int o = tid + half * 256;
      const float* wrow = W1 + (size_t)o * 2048;
      float a0 = 0.f, a1 = 0.f, a2 = 0.f, a3 = 0.f;
      for (int k = 0; k < 2048; k += 16) {
        float4 w0 = *(const float4*)(wrow + k);
        float4 w1v = *(const float4*)(wrow + k + 4);
        float4 w2v = *(const float4*)(wrow + k + 8);
        float4 w3v = *(const float4*)(wrow + k + 12);
        float4 x0 = *(const float4*)(h_sh + k);
        float4 x1 = *(const float4*)(h_sh + k + 4);
        float4 x2 = *(const float4*)(h_sh + k + 8);
        float4 x3 = *(const float4*)(h_sh + k + 12);
        a0 += w0.x*x0.x + w0.y*x0.y + w0.z*x0.z + w0.w*x0.w;
        a1 += w1v.x*x1.x + w1v.y*x1.y + w1v.z*x1.z + w1v.w*x1.w;
        a2 += w2v.x*x2.x + w2v.y*x2.y + w2v.z*x2.z + w2v.w*x2.w;
        a3 += w3v.x*x3.x + w3v.y*x3.y + w3v.z*x3.z + w3v.w*x3.w;
      }
      hid_sh[o] = fmaxf((a0 + a1) + (a2 + a3) + b1[o], 0.0f);
    }
    __syncthreads();
    if (tid < 64) {
      const int lane = tid;
      const float* hs = &hid_sh[lane * 8];
      float l[3];
      #pragma unroll
      for (int c = 0; c < 3; c++) {
        const float* w = W2 + c * 512 + lane * 8;
        float s = 0.0f;
        #pragma unroll
        for (int e = 0; e < 8; e++) s += hs[e] * w[e];
        l[c] = s;
      }
      #pragma unroll
      for (int off = 32; off >= 1; off >>= 1)
        #pragma unroll
        for (int c = 0; c < 3; c++) l[c] += __shfl_xor(l[c], off, 64);
      if (lane == 0) {
        float l0 = l[0] + b2[0], l1 = l[1] + b2[1], l2 = l[2] + b2[2];
        int arg = 0; float best = l0;
        if (l1 > best) { best = l1; arg = 1; }
        if (l2 > best) { arg = 2; }
        sel[token] = arg;
      }
    }
    __syncthreads();
  }
}

__global__ __launch_bounds__(256)
void copy_sel0(const float* __restrict__ h, const int* __restrict__ sel,
               float* __restrict__ out) {
  const int token = blockIdx.x;
  if (sel[token] != 0) return;
  const float4* src = (const float4*)(h + (size_t)token * 2048);
  float4* dst = (float4*)(out + (size_t)token * 2048);
  dst[threadIdx.x] = src[threadIdx.x];
  dst[threadIdx.x + 256] = src[threadIdx.x + 256];
}

extern "C" void kernel_launch(void* const* d_in, const int* in_sizes, int n_in,
                              void* d_out, int out_size, void* d_ws, size_t ws_size,
                              hipStream_t stream) {
  const float* h        = (const float*)d_in[0];
  const float* freq     = (const float*)d_in[1];
  const float* imp      = (const float*)d_in[2];
  const float* comp1W   = (const float*)d_in[3];
  const float* comp1b   = (const float*)d_in[4];
  const float* adapt1W  = (const float*)d_in[5];
  const float* adapt1b  = (const float*)d_in[6];
  const float* decomp1W = (const float*)d_in[7];
  const float* decomp1b = (const float*)d_in[8];
  const float* comp2W   = (const float*)d_in[9];
  const float* comp2b   = (const float*)d_in[10];
  const float* adapt2W  = (const float*)d_in[11];
  const float* adapt2b  = (const float*)d_in[12];
  const float* decomp2W = (const float*)d_in[13];
  const float* decomp2b = (const float*)d_in[14];
  const float* sel1W    = (const float*)d_in[15];
  const float* sel1b    = (const float*)d_in[16];
  const float* sel2W    = (const float*)d_in[17];
  const float* sel2b    = (const float*)d_in[18];
  float* out = (float*)d_out;

  char* ws = (char*)d_ws;
  size_t off = 0;
  auto alloc = [&](size_t bytes) -> void* {
    void* p = ws + off; off += (bytes + 255) & ~(size_t)255; return p;
  };
  unsigned short* wb_comp1   = (unsigned short*)alloc((size_t)1024 * 2048 * 2);
  unsigned short* wb_adapt1  = (unsigned short*)alloc((size_t)1024 * 1024 * 2);
  unsigned short* wb_decomp1 = (unsigned short*)alloc((size_t)2048 * 1024 * 2);
  unsigned short* wb_comp2   = (unsigned short*)alloc((size_t)512 * 2048 * 2);
  unsigned short* wb_adapt2  = (unsigned short*)alloc((size_t)512 * 512 * 2);
  unsigned short* wb_decomp2 = (unsigned short*)alloc((size_t)2048 * 512 * 2);
  unsigned short* w1hi       = (unsigned short*)alloc((size_t)512 * 2048 * 2);
  unsigned short* w1lo       = (unsigned short*)alloc((size_t)512 * 2048 * 2);
  float*          hidf       = (float*)alloc((size_t)TOK * 512 * 4);
  unsigned short* c1         = (unsigned short*)alloc((size_t)TOK * 1024 * 2);
  unsigned short* a1         = (unsigned short*)alloc((size_t)TOK * 1024 * 2);
  int* sel        = (int*)alloc((size_t)TOK * 4);
  int* risky      = (int*)alloc((size_t)TOK * 4);
  int* riskyCount = (int*)alloc(256);
  int* idx1       = (int*)alloc((size_t)TOK * 4);
  int* idx2       = (int*)alloc((size_t)TOK * 4);
  int* cnt        = (int*)alloc(256);   // [0]=n1, [1]=n2
  int* mc         = (int*)alloc(256);   // [0]=p1, [1]=p2 (padded to 128)
  // total ws: ~115 MB (identical to round-1 passing footprint)

  // hb (bf16 h, 64 MB) lives in the FIRST HALF OF out; dead before any out
  // writes (comp1+comp2 both run before decomp/copy stages).
  unsigned short* hb = (unsigned short*)out;
  // branch-2 intermediates alias hidf (dead after selector_logits_f32)
  unsigned short* c2 = (unsigned short*)hidf;                       // <=16 MB
  unsigned short* a2 = (unsigned short*)hidf + (size_t)TOK * 512;   // <=16 MB

  zero3<<<1, 64, 0, stream>>>(riskyCount, cnt);

  auto cvt = [&](const float* s, unsigned short* d, int n) {
    cvt_kernel<<<(n / 4 + 255) / 256, 256, 0, stream>>>(s, d, n / 4);
  };
  cvt(comp1W,   wb_comp1,   1024 * 2048);
  cvt(adapt1W,  wb_adapt1,  1024 * 1024);
  cvt(decomp1W, wb_decomp1, 2048 * 1024);
  cvt(comp2W,   wb_comp2,   512 * 2048);
  cvt(adapt2W,  wb_adapt2,  512 * 512);
  cvt(decomp2W, wb_decomp2, 2048 * 512);
  cvt(h,        hb,         TOK * 2048);   // bf16 copy of h (same rounding as
                                           // the old in-kernel convert)
  cvt_split_kernel<<<(512 * 2048 / 4 + 255) / 256, 256, 0, stream>>>(
      sel1W, w1hi, w1lo, 512 * 2048 / 4);

  // selector: hid = relu(combined @ sel1W^T + b) in split-bf16, fp32 store
  gemm_sel<<<dim3(512 / 128, TOK / 128), 256, 0, stream>>>(
      h, w1hi, w1lo, sel1b, hidf, freq, imp, 512, 2048);
  selector_logits_f32<<<TOK / 4, 256, 0, stream>>>(hidf, sel2W, sel2b, sel, risky, riskyCount);
  recheck_exact<<<256, 256, 0, stream>>>(h, freq, imp, sel1W, sel1b, sel2W, sel2b,
                                         risky, riskyCount, sel);

  // token compaction: branch GEMMs only run over their selected tokens
  compact_sel<<<TOK / 256, 256, 0, stream>>>(sel, idx1, idx2, cnt);
  pad_idx<<<1, 256, 0, stream>>>(idx1, idx2, cnt, mc);

  // both comp GEMMs first (they read hb, which lives in out)
  gemm_bf16<0, 1><<<dim3(1024 / 128, TOK / 128), 256, 0, stream>>>(
      hb, wb_comp1, comp1b, c1, idx1, mc + 0, 1024, 2048);
  gemm_bf16<0, 1><<<dim3(512 / 128, TOK / 128), 256, 0, stream>>>(
      hb, wb_comp2, comp2b, c2, idx2, mc + 1, 512, 2048);
  // adaptors
  gemm_bf16<0, 0><<<dim3(1024 / 128, TOK / 128), 256, 0, stream>>>(
      c1, wb_adapt1, adapt1b, a1, nullptr, mc + 0, 1024, 1024);
  gemm_bf16<0, 0><<<dim3(512 / 128, TOK / 128), 256, 0, stream>>>(
      c2, wb_adapt2, adapt2b, a2, nullptr, mc + 1, 512, 512);
  // decompressors scatter into out (hb now dead)
  gemm_bf16<4, 0><<<dim3(2048 / 128, TOK / 128), 256, 0, stream>>>(
      a1, wb_decomp1, decomp1b, out, idx1, mc + 0, 2048, 1024);
  gemm_bf16<4, 0><<<dim3(2048 / 128, TOK / 128), 256, 0, stream>>>(
      a2, wb_decomp2, decomp2b, out, idx2, mc + 1, 2048, 512);

  // sel==0 tokens: exact fp32 passthrough of h
  copy_sel0<<<TOK, 256, 0, stream>>>(h, sel, out);
}

// Round 4
// 952.781 us; speedup vs baseline: 1.1122x; 1.0269x over previous
//
#include <hip/hip_runtime.h>
#include <hip/hip_bf16.h>

#define TOK 16384
#define TAU2 0.001f

typedef __attribute__((ext_vector_type(8))) short short8;
typedef __attribute__((ext_vector_type(4))) float f32x4;

__device__ __forceinline__ unsigned short f32_bf16(float f) {
  __hip_bfloat16 h = __float2bfloat16(f);
  unsigned short u;
  __builtin_memcpy(&u, &h, sizeof(u));
  return u;
}
__device__ __forceinline__ float bf16_f32(unsigned short u) {
  union { unsigned int i; float f; } c; c.i = ((unsigned int)u) << 16; return c.f;
}

// async global->LDS, 16B per lane; LDS dest linear in lane order.
__device__ __forceinline__ void gll16(const unsigned short* g, unsigned short* l) {
  __builtin_amdgcn_global_load_lds(
      (const __attribute__((address_space(1))) unsigned int*)g,
      (__attribute__((address_space(3))) unsigned int*)l, 16, 0, 0);
}

__global__ void zero3(int* a, int* c) {
  if (threadIdx.x == 0) { *a = 0; c[0] = 0; c[1] = 0; }
}

__global__ void cvt_kernel(const float* __restrict__ s, unsigned short* __restrict__ d, int n4) {
  int i = blockIdx.x * 256 + threadIdx.x;
  if (i < n4) {
    float4 v = ((const float4*)s)[i];
    union { unsigned short u[4]; uint2 q; } pk;
    pk.u[0] = f32_bf16(v.x); pk.u[1] = f32_bf16(v.y);
    pk.u[2] = f32_bf16(v.z); pk.u[3] = f32_bf16(v.w);
    ((uint2*)d)[i] = pk.q;
  }
}

// split fp32 -> (hi, lo) bf16 pair: hi = bf16(v), lo = bf16(v - f32(hi))
__global__ void cvt_split_kernel(const float* __restrict__ s,
                                 unsigned short* __restrict__ dhi,
                                 unsigned short* __restrict__ dlo, int n4) {
  int i = blockIdx.x * 256 + threadIdx.x;
  if (i < n4) {
    float4 v = ((const float4*)s)[i];
    const float* f = (const float*)&v;
    union { unsigned short u[4]; uint2 q; } hi, lo;
    #pragma unroll
    for (int e = 0; e < 4; e++) {
      unsigned short h = f32_bf16(f[e]);
      hi.u[e] = h;
      lo.u[e] = f32_bf16(f[e] - bf16_f32(h));
    }
    ((uint2*)dhi)[i] = hi.q;
    ((uint2*)dlo)[i] = lo.q;
  }
}

// token compaction by selected branch (runs after sel is final)
__global__ void compact_sel(const int* __restrict__ sel, int* __restrict__ idx1,
                            int* __restrict__ idx2, int* __restrict__ cnt) {
  int t = blockIdx.x * 256 + threadIdx.x;
  int s = sel[t];
  if (s == 1) idx1[atomicAdd(&cnt[0], 1)] = t;
  else if (s == 2) idx2[atomicAdd(&cnt[1], 1)] = t;
}

// pad index lists to a multiple of 128 with -1 sentinels; publish padded counts
__global__ void pad_idx(int* __restrict__ idx1, int* __restrict__ idx2,
                        const int* __restrict__ cnt, int* __restrict__ mc) {
  const int tid = threadIdx.x;
  const int n1 = cnt[0], n2 = cnt[1];
  const int p1 = (n1 + 127) & ~(int)127, p2 = (n2 + 127) & ~(int)127;
  if (tid < p1 - n1) idx1[n1 + tid] = -1;
  if (tid < p2 - n2) idx2[n2 + tid] = -1;
  if (tid == 0) { mc[0] = p1; mc[1] = p2; }
}

// ---------------------------------------------------------------------------
// bf16 GEMM body: 128x128 tile, BK=32, 32 KB LDS double-buffer (m99 operating
// point: 3 blocks/CU), one barrier per k-step, global_load_lds staging
// (16B/lane, linear LDS dest), 4-chunk XOR swizzle (write-side via
// pre-swizzled global source chunk, read-side matching XOR) -> 4-way max
// ds_read_b128 conflicts (was 8-way).
// C[M,N] = A[M,K] * Bw[N,K]^T + bias
// EPI: 0 = bf16 store, 4 = fp32 scatter store to out row idx[row] (skip idx<0)
// AG:  1 = gather A rows through idx (sentinel -1 clamps to row 0)
// mcp: active row count (padded to 128); blocks past it exit.
// ---------------------------------------------------------------------------
template<int EPI, int AG>
__device__ __forceinline__
void gemm_body(const unsigned short* __restrict__ A,
               const unsigned short* __restrict__ Bw,
               const float* __restrict__ bias,
               void* __restrict__ Outv,
               const int* __restrict__ idx, const int* __restrict__ mcp,
               int N, int K) {
  __shared__ __align__(16) unsigned short As[2][128 * 32];
  __shared__ __align__(16) unsigned short Bs[2][128 * 32];
  const int tid = threadIdx.x;
  const int m0 = blockIdx.y * 128, n0 = blockIdx.x * 128;
  if (mcp && m0 >= *mcp) return;
  const int lane = tid & 63, wave = tid >> 6;
  const int wm = wave >> 1, wn = wave & 1;
  const int quad = lane >> 4, lr = lane & 15;

  // staging: round r in {0,1}; thread t covers row r*64 + (t>>2), chunk t&3
  // (16B chunks of a 64B row). LDS dest linear = t*16B; its content must be
  // global chunk (t&3) ^ (row&3).
  const int srow = tid >> 2;                   // 0..63
  const int schunk = (tid & 3) ^ (srow & 3);   // pre-swizzled source chunk
  unsigned int aoff[2], boff[2];
  #pragma unroll
  for (int r = 0; r < 2; r++) {
    int row = r * 64 + srow;
    int gr = m0 + row;
    if (AG) { int t = idx[gr]; gr = (t < 0) ? 0 : t; }
    aoff[r] = (unsigned int)gr * (unsigned int)K + (unsigned int)(schunk * 8);
    boff[r] = (unsigned int)(n0 + row) * (unsigned int)K + (unsigned int)(schunk * 8);
  }
  const int lds_dst = tid * 8;  // shorts; round r adds 2048

  f32x4 acc[4][4] = {};
  const int nk = K >> 5;

  // prologue: stage k-tile 0
  #pragma unroll
  for (int r = 0; r < 2; r++) {
    gll16(A + aoff[r], &As[0][r * 2048 + lds_dst]);
    gll16(Bw + boff[r], &Bs[0][r * 2048 + lds_dst]);
  }
  __syncthreads();

  int cur = 0;
  for (int t = 0; t < nk; t++) {
    if (t + 1 < nk) {
      const unsigned int k0 = (unsigned int)(t + 1) << 5;
      #pragma unroll
      for (int r = 0; r < 2; r++) {
        gll16(A + aoff[r] + k0, &As[cur ^ 1][r * 2048 + lds_dst]);
        gll16(Bw + boff[r] + k0, &Bs[cur ^ 1][r * 2048 + lds_dst]);
      }
    }
    short8 af[4], bfr[4];
    #pragma unroll
    for (int i = 0; i < 4; i++) {
      const int row = wm * 64 + i * 16 + lr;
      af[i] = *(const short8*)(&As[cur][row * 32 + ((quad ^ (row & 3)) << 3)]);
    }
    #pragma unroll
    for (int j = 0; j < 4; j++) {
      const int row = wn * 64 + j * 16 + lr;
      bfr[j] = *(const short8*)(&Bs[cur][row * 32 + ((quad ^ (row & 3)) << 3)]);
    }
    #pragma unroll
    for (int i = 0; i < 4; i++)
      #pragma unroll
      for (int j = 0; j < 4; j++)
        acc[i][j] = __builtin_amdgcn_mfma_f32_16x16x32_bf16(af[i], bfr[j], acc[i][j], 0, 0, 0);
    __syncthreads();  // drains vmcnt (prefetch landed) + all waves done with cur
    cur ^= 1;
  }

  // epilogue: C/D layout col=lane&15 (n), row=quad*4+reg (m)
  #pragma unroll
  for (int i = 0; i < 4; i++) {
    const int rbase = m0 + wm * 64 + i * 16 + quad * 4;
    #pragma unroll
    for (int j = 0; j < 4; j++) {
      const int col = n0 + wn * 64 + j * 16 + lr;
      const float bv = bias[col];
      #pragma unroll
      for (int r = 0; r < 4; r++) {
        const int row = rbase + r;
        float v = acc[i][j][r] + bv;
        if (EPI == 0) {
          ((unsigned short*)Outv)[(size_t)row * N + col] = f32_bf16(v);
        } else {  // EPI == 4
          const int tk = idx[row];
          if (tk >= 0) ((float*)Outv)[(size_t)tk * N + col] = v;
        }
      }
    }
  }
}

// named shells so rocprof shows per-stage durations
#define GEMM_SHELL(NAME, EPI, AG)                                              \
__global__ __launch_bounds__(256, 3) void NAME(                                \
    const unsigned short* __restrict__ A,                                      \
    const unsigned short* __restrict__ Bw,                                     \
    const float* __restrict__ bias, void* __restrict__ Outv,                   \
    const int* __restrict__ idx, const int* __restrict__ mcp, int N, int K) {  \
  gemm_body<EPI, AG>(A, Bw, bias, Outv, idx, mcp, N, K);                       \
}
GEMM_SHELL(g_comp1, 0, 1)
GEMM_SHELL(g_comp2, 0, 1)
GEMM_SHELL(g_adapt1, 0, 0)
GEMM_SHELL(g_adapt2, 0, 0)
GEMM_SHELL(g_dec1, 4, 0)
GEMM_SHELL(g_dec2, 4, 0)

// ---------------------------------------------------------------------------
// selector GEMM (unchanged, proven): fp32 A scaled per row-half, split hi/lo
// bf16; 3 MFMAs per fragment pair; relu + fp32 store.
// ---------------------------------------------------------------------------
__global__ __launch_bounds__(256, 2)
void gemm_sel(const float* __restrict__ Af,
              const unsigned short* __restrict__ Bw,
              const unsigned short* __restrict__ Bw2,
              const float* __restrict__ bias,
              float* __restrict__ Out,
              const float* __restrict__ scA, const float* __restrict__ scB,
              int N, int K) {
  __shared__ __align__(16) unsigned short As[2 * 128 * 32];
  __shared__ __align__(16) unsigned short Bs[2 * 128 * 32];
  const int LO = 128 * 32;
  const int tid = threadIdx.x;
  const int m0 = blockIdx.y * 128, n0 = blockIdx.x * 128;
  const int lane = tid & 63, wave = tid >> 6;
  const int wm = wave >> 1, wn = wave & 1;
  const int quad = lane >> 4, lr = lane & 15;
  const int srow = tid >> 1, scol = (tid & 1) * 16;

  const size_t aRowOff = (size_t)(m0 + srow) * K;
  const unsigned short* Brow = Bw + (size_t)(n0 + srow) * K;
  const unsigned short* Brow2 = Bw2 + (size_t)(n0 + srow) * K;

  f32x4 acc[4][4] = {};

  for (int k0 = 0; k0 < K; k0 += 32) {
    {
      const float4* src = (const float4*)(Af + aRowOff + k0 + scol);
      float4 f[4];
      f[0] = src[0]; f[1] = src[1]; f[2] = src[2]; f[3] = src[3];
      const int tk = m0 + srow;
      const float s = ((k0 + scol) * 2 < K) ? scA[tk] : scB[tk];
      union { unsigned short u[16]; uint4 q[2]; } hi;
      union { unsigned short u[16]; uint4 q[2]; } lo;
      const float* ff = (const float*)f;
      #pragma unroll
      for (int e = 0; e < 16; e++) {
        float fv = ff[e] * s;
        unsigned short hb = f32_bf16(fv);
        hi.u[e] = hb;
        lo.u[e] = f32_bf16(fv - bf16_f32(hb));
      }
      uint4* dst = (uint4*)(As + srow * 32 + scol);
      dst[0] = hi.q[0]; dst[1] = hi.q[1];
      uint4* dst2 = (uint4*)(As + LO + srow * 32 + scol);
      dst2[0] = lo.q[0]; dst2[1] = lo.q[1];
    }
    {
      const uint4* src = (const uint4*)(Brow + k0 + scol);
      uint4* dst = (uint4*)(Bs + srow * 32 + scol);
      dst[0] = src[0]; dst[1] = src[1];
      const uint4* src2 = (const uint4*)(Brow2 + k0 + scol);
      uint4* dst2 = (uint4*)(Bs + LO + srow * 32 + scol);
      dst2[0] = src2[0]; dst2[1] = src2[1];
    }
    __syncthreads();
    short8 af[4], bfr[4], af2[4], bf2[4];
    #pragma unroll
    for (int i = 0; i < 4; i++) {
      af[i]  = *(const short8*)(As + (wm * 64 + i * 16 + lr) * 32 + quad * 8);
      af2[i] = *(const short8*)(As + LO + (wm * 64 + i * 16 + lr) * 32 + quad * 8);
    }
    #pragma unroll
    for (int j = 0; j < 4; j++) {
      bfr[j] = *(const short8*)(Bs + (wn * 64 + j * 16 + lr) * 32 + quad * 8);
      bf2[j] = *(const short8*)(Bs + LO + (wn * 64 + j * 16 + lr) * 32 + quad * 8);
    }
    #pragma unroll
    for (int i = 0; i < 4; i++)
      #pragma unroll
      for (int j = 0; j < 4; j++) {
        acc[i][j] = __builtin_amdgcn_mfma_f32_16x16x32_bf16(af[i], bfr[j], acc[i][j], 0, 0, 0);
        acc[i][j] = __builtin_amdgcn_mfma_f32_16x16x32_bf16(af[i], bf2[j], acc[i][j], 0, 0, 0);
        acc[i][j] = __builtin_amdgcn_mfma_f32_16x16x32_bf16(af2[i], bfr[j], acc[i][j], 0, 0, 0);
      }
    __syncthreads();
  }

  #pragma unroll
  for (int i = 0; i < 4; i++) {
    const int rbase = m0 + wm * 64 + i * 16 + quad * 4;
    #pragma unroll
    for (int j = 0; j < 4; j++) {
      const int col = n0 + wn * 64 + j * 16 + lr;
      const float bv = bias[col];
      #pragma unroll
      for (int r = 0; r < 4; r++) {
        const int row = rbase + r;
        float v = acc[i][j][r] + bv;
        Out[(size_t)row * N + col] = fmaxf(v, 0.0f);
      }
    }
  }
}

// logits from fp32 hid, argmax + tight margin flagging. One wave per token.
__global__ __launch_bounds__(256)
void selector_logits_f32(const float* __restrict__ hidf,
                         const float* __restrict__ W2, const float* __restrict__ b2,
                         int* __restrict__ sel, int* __restrict__ risky,
                         int* __restrict__ riskyCount) {
  const int wave = threadIdx.x >> 6, lane = threadIdx.x & 63;
  const int token = blockIdx.x * 4 + wave;
  const float* hs = hidf + (size_t)token * 512 + lane * 8;
  float4 h0 = *(const float4*)hs, h1 = *(const float4*)(hs + 4);
  float p[3];
  #pragma unroll
  for (int c = 0; c < 3; c++) {
    const float* w = W2 + c * 512 + lane * 8;
    float4 w0 = *(const float4*)w, w1 = *(const float4*)(w + 4);
    p[c] = h0.x*w0.x + h0.y*w0.y + h0.z*w0.z + h0.w*w0.w
         + h1.x*w1.x + h1.y*w1.y + h1.z*w1.z + h1.w*w1.w;
  }
  #pragma unroll
  for (int off = 32; off >= 1; off >>= 1) {
    #pragma unroll
    for (int c = 0; c < 3; c++) p[c] += __shfl_xor(p[c], off, 64);
  }
  if (lane == 0) {
    float l0 = p[0] + b2[0], l1 = p[1] + b2[1], l2 = p[2] + b2[2];
    int arg = 0; float best = l0;
    if (l1 > best) { best = l1; arg = 1; }
    if (l2 > best) { best = l2; arg = 2; }
    float second;
    if (arg == 0) second = fmaxf(l1, l2);
    else if (arg == 1) second = fmaxf(l0, l2);
    else second = fmaxf(l0, l1);
    sel[token] = arg;
    if (best - second < TAU2) {
      int idx = atomicAdd(riskyCount, 1);
      risky[idx] = token;
    }
  }
}

// exact fp32 selector recompute for ultra-near-tie tokens (~100 expected).
__global__ __launch_bounds__(256)
void recheck_exact(const float* __restrict__ h, const float* __restrict__ freq,
                   const float* __restrict__ imp,
                   const float* __restrict__ W1, const float* __restrict__ b1,
                   const float* __restrict__ W2, const float* __restrict__ b2,
                   const int* __restrict__ risky, const int* __restrict__ riskyCount,
                   int* __restrict__ sel) {
  __shared__ float h_sh[2048];
  __shared__ float hid_sh[512];
  const int n = *riskyCount;
  const int tid = threadIdx.x;
  for (int ri = blockIdx.x; ri < n; ri += gridDim.x) {
    const int token = risky[ri];
    {
      const float s = (tid < 128) ? freq[token] : imp[token];
      const float4* src = (const float4*)(h + (size_t)token * 2048) + tid * 2;
      float4 v0 = src[0], v1 = src[1];
      v0.x *= s; v0.y *= s; v0.z *= s; v0.w *= s;
      v1.x *= s; v1.y *= s; v1.z *= s; v1.w *= s;
      ((float4*)h_sh)[tid * 2] = v0;
      ((float4*)h_sh)[tid * 2 + 1] = v1;
    }
    __syncthreads();
    #pragma unroll
    for (int half = 0; half < 2; half++) {
      const int o = tid + half * 256;
      const float* wrow = W1 + (size_t)o * 2048;
      float a0 = 0.f, a1 = 0.f, a2 = 0.f, a3 = 0.f;
      for (int k = 0; k < 2048; k += 16) {
        float4 w0 = *(const float4*)(wrow + k);
        float4 w1v = *(const float4*)(wrow + k + 4);
        float4 w2v = *(const float4*)(wrow + k + 8);
        float4 w3v = *(const float4*)(wrow + k + 12);
        float4 x0 = *(const float4*)(h_sh + k);
        float4 x1 = *(const float4*)(h_sh + k + 4);
        float4 x2 = *(const float4*)(h_sh + k + 8);
        float4 x3 = *(const float4*)(h_sh + k + 12);
        a0 += w0.x*x0.x + w0.y*x0.y + w0.z*x0.z + w0.w*x0.w;
        a1 += w1v.x*x1.x + w1v.y*x1.y + w1v.z*x1.z + w1v.w*x1.w;
        a2 += w2v.x*x2.x + w2v.y*x2.y + w2v.z*x2.z + w2v.w*x2.w;
        a3 += w3v.x*x3.x + w3v.y*x3.y + w3v.z*x3.z + w3v.w*x3.w;
      }
      hid_sh[o] = fmaxf((a0 + a1) + (a2 + a3) + b1[o], 0.0f);
    }
    __syncthreads();
    if (tid < 64) {
      const int lane = tid;
      const float* hs = &hid_sh[lane * 8];
      float l[3];
      #pragma unroll
      for (int c = 0; c < 3; c++) {
        const float* w = W2 + c * 512 + lane * 8;
        float s = 0.0f;
        #pragma unroll
        for (int e = 0; e < 8; e++) s += hs[e] * w[e];
        l[c] = s;
      }
      #pragma unroll
      for (int off = 32; off >= 1; off >>= 1)
        #pragma unroll
        for (int c = 0; c < 3; c++) l[c] += __shfl_xor(l[c], off, 64);
      if (lane == 0) {
        float l0 = l[0] + b2[0], l1 = l[1] + b2[1], l2 = l[2] + b2[2];
        int arg = 0; float best = l0;
        if (l1 > best) { best = l1; arg = 1; }
        if (l2 > best) { arg = 2; }
        sel[token] = arg;
      }
    }
    __syncthreads();
  }
}

__global__ __launch_bounds__(256)
void copy_sel0(const float* __restrict__ h, const int* __restrict__ sel,
               float* __restrict__ out) {
  const int token = blockIdx.x;
  if (sel[token] != 0) return;
  const float4* src = (const float4*)(h + (size_t)token * 2048);
  float4* dst = (float4*)(out + (size_t)token * 2048);
  dst[threadIdx.x] = src[threadIdx.x];
  dst[threadIdx.x + 256] = src[threadIdx.x + 256];
}

extern "C" void kernel_launch(void* const* d_in, const int* in_sizes, int n_in,
                              void* d_out, int out_size, void* d_ws, size_t ws_size,
                              hipStream_t stream) {
  const float* h        = (const float*)d_in[0];
  const float* freq     = (const float*)d_in[1];
  const float* imp      = (const float*)d_in[2];
  const float* comp1W   = (const float*)d_in[3];
  const float* comp1b   = (const float*)d_in[4];
  const float* adapt1W  = (const float*)d_in[5];
  const float* adapt1b  = (const float*)d_in[6];
  const float* decomp1W = (const float*)d_in[7];
  const float* decomp1b = (const float*)d_in[8];
  const float* comp2W   = (const float*)d_in[9];
  const float* comp2b   = (const float*)d_in[10];
  const float* adapt2W  = (const float*)d_in[11];
  const float* adapt2b  = (const float*)d_in[12];
  const float* decomp2W = (const float*)d_in[13];
  const float* decomp2b = (const float*)d_in[14];
  const float* sel1W    = (const float*)d_in[15];
  const float* sel1b    = (const float*)d_in[16];
  const float* sel2W    = (const float*)d_in[17];
  const float* sel2b    = (const float*)d_in[18];
  float* out = (float*)d_out;

  char* ws = (char*)d_ws;
  size_t off = 0;
  auto alloc = [&](size_t bytes) -> void* {
    void* p = ws + off; off += (bytes + 255) & ~(size_t)255; return p;
  };
  unsigned short* wb_comp1   = (unsigned short*)alloc((size_t)1024 * 2048 * 2);
  unsigned short* wb_adapt1  = (unsigned short*)alloc((size_t)1024 * 1024 * 2);
  unsigned short* wb_decomp1 = (unsigned short*)alloc((size_t)2048 * 1024 * 2);
  unsigned short* wb_comp2   = (unsigned short*)alloc((size_t)512 * 2048 * 2);
  unsigned short* wb_adapt2  = (unsigned short*)alloc((size_t)512 * 512 * 2);
  unsigned short* wb_decomp2 = (unsigned short*)alloc((size_t)2048 * 512 * 2);
  unsigned short* w1hi       = (unsigned short*)alloc((size_t)512 * 2048 * 2);
  unsigned short* w1lo       = (unsigned short*)alloc((size_t)512 * 2048 * 2);
  float*          hidf       = (float*)alloc((size_t)TOK * 512 * 4);
  unsigned short* c1         = (unsigned short*)alloc((size_t)TOK * 1024 * 2);
  unsigned short* a1         = (unsigned short*)alloc((size_t)TOK * 1024 * 2);
  int* sel        = (int*)alloc((size_t)TOK * 4);
  int* risky      = (int*)alloc((size_t)TOK * 4);
  int* riskyCount = (int*)alloc(256);
  int* idx1       = (int*)alloc((size_t)TOK * 4);
  int* idx2       = (int*)alloc((size_t)TOK * 4);
  int* cnt        = (int*)alloc(256);   // [0]=n1, [1]=n2
  int* mc         = (int*)alloc(256);   // [0]=p1, [1]=p2 (padded to 128)
  // total ws: ~115 MB (proven footprint)

  // hb (bf16 h, 64 MB) lives in the FIRST HALF OF out; dead before any out
  // writes (comp1+comp2 both run before decomp/copy stages).
  unsigned short* hb = (unsigned short*)out;
  // branch-2 intermediates alias hidf (dead after selector_logits_f32)
  unsigned short* c2 = (unsigned short*)hidf;                       // 16 MB
  unsigned short* a2 = (unsigned short*)hidf + (size_t)TOK * 512;   // 16 MB

  zero3<<<1, 64, 0, stream>>>(riskyCount, cnt);

  auto cvt = [&](const float* s, unsigned short* d, int n) {
    cvt_kernel<<<(n / 4 + 255) / 256, 256, 0, stream>>>(s, d, n / 4);
  };
  cvt(comp1W,   wb_comp1,   1024 * 2048);
  cvt(adapt1W,  wb_adapt1,  1024 * 1024);
  cvt(decomp1W, wb_decomp1, 2048 * 1024);
  cvt(comp2W,   wb_comp2,   512 * 2048);
  cvt(adapt2W,  wb_adapt2,  512 * 512);
  cvt(decomp2W, wb_decomp2, 2048 * 512);
  cvt(h,        hb,         TOK * 2048);   // bf16 copy of h
  cvt_split_kernel<<<(512 * 2048 / 4 + 255) / 256, 256, 0, stream>>>(
      sel1W, w1hi, w1lo, 512 * 2048 / 4);

  // selector: hid = relu(combined @ sel1W^T + b) in split-bf16, fp32 store
  gemm_sel<<<dim3(512 / 128, TOK / 128), 256, 0, stream>>>(
      h, w1hi, w1lo, sel1b, hidf, freq, imp, 512, 2048);
  selector_logits_f32<<<TOK / 4, 256, 0, stream>>>(hidf, sel2W, sel2b, sel, risky, riskyCount);
  recheck_exact<<<256, 256, 0, stream>>>(h, freq, imp, sel1W, sel1b, sel2W, sel2b,
                                         risky, riskyCount, sel);

  // token compaction: branch GEMMs only run over their selected tokens
  compact_sel<<<TOK / 256, 256, 0, stream>>>(sel, idx1, idx2, cnt);
  pad_idx<<<1, 256, 0, stream>>>(idx1, idx2, cnt, mc);

  // both comp GEMMs first (they read hb, which lives in out)
  g_comp1<<<dim3(1024 / 128, TOK / 128), 256, 0, stream>>>(
      hb, wb_comp1, comp1b, c1, idx1, mc + 0, 1024, 2048);
  g_comp2<<<dim3(512 / 128, TOK / 128), 256, 0, stream>>>(
      hb, wb_comp2, comp2b, c2, idx2, mc + 1, 512, 2048);
  // adaptors
  g_adapt1<<<dim3(1024 / 128, TOK / 128), 256, 0, stream>>>(
      c1, wb_adapt1, adapt1b, a1, nullptr, mc + 0, 1024, 1024);
  g_adapt2<<<dim3(512 / 128, TOK / 128), 256, 0, stream>>>(
      c2, wb_adapt2, adapt2b, a2, nullptr, mc + 1, 512, 512);
  // decompressors scatter into out (hb now dead)
  g_dec1<<<dim3(2048 / 128, TOK / 128), 256, 0, stream>>>(
      a1, wb_decomp1, decomp1b, out, idx1, mc + 0, 2048, 1024);
  g_dec2<<<dim3(2048 / 128, TOK / 128), 256, 0, stream>>>(
      a2, wb_decomp2, decomp2b, out, idx2, mc + 1, 2048, 512);

  // sel==0 tokens: exact fp32 passthrough of h
  copy_sel0<<<TOK, 256, 0, stream>>>(h, sel, out);
}

// Round 5
// 938.202 us; speedup vs baseline: 1.1295x; 1.0155x over previous
//
#include <hip/hip_runtime.h>
#include <hip/hip_bf16.h>

#define TOK 16384
#define TAU2 0.001f
#define CFENCE asm volatile("" ::: "memory")

typedef __attribute__((ext_vector_type(8))) short short8;
typedef __attribute__((ext_vector_type(4))) float f32x4;

__device__ __forceinline__ unsigned short f32_bf16(float f) {
  __hip_bfloat16 h = __float2bfloat16(f);
  unsigned short u;
  __builtin_memcpy(&u, &h, sizeof(u));
  return u;
}
__device__ __forceinline__ float bf16_f32(unsigned short u) {
  union { unsigned int i; float f; } c; c.i = ((unsigned int)u) << 16; return c.f;
}

// async global->LDS, 16B per lane; LDS dest linear in lane order.
__device__ __forceinline__ void gll16(const unsigned short* g, unsigned short* l) {
  __builtin_amdgcn_global_load_lds(
      (const __attribute__((address_space(1))) unsigned int*)g,
      (__attribute__((address_space(3))) unsigned int*)l, 16, 0, 0);
}

__global__ void zero3(int* a, int* c) {
  if (threadIdx.x == 0) { *a = 0; c[0] = 0; c[1] = 0; }
}

__global__ void cvt_kernel(const float* __restrict__ s, unsigned short* __restrict__ d, int n4) {
  int i = blockIdx.x * 256 + threadIdx.x;
  if (i < n4) {
    float4 v = ((const float4*)s)[i];
    union { unsigned short u[4]; uint2 q; } pk;
    pk.u[0] = f32_bf16(v.x); pk.u[1] = f32_bf16(v.y);
    pk.u[2] = f32_bf16(v.z); pk.u[3] = f32_bf16(v.w);
    ((uint2*)d)[i] = pk.q;
  }
}

// split fp32 -> (hi, lo) bf16 pair: hi = bf16(v), lo = bf16(v - f32(hi))
__global__ void cvt_split_kernel(const float* __restrict__ s,
                                 unsigned short* __restrict__ dhi,
                                 unsigned short* __restrict__ dlo, int n4) {
  int i = blockIdx.x * 256 + threadIdx.x;
  if (i < n4) {
    float4 v = ((const float4*)s)[i];
    const float* f = (const float*)&v;
    union { unsigned short u[4]; uint2 q; } hi, lo;
    #pragma unroll
    for (int e = 0; e < 4; e++) {
      unsigned short h = f32_bf16(f[e]);
      hi.u[e] = h;
      lo.u[e] = f32_bf16(f[e] - bf16_f32(h));
    }
    ((uint2*)dhi)[i] = hi.q;
    ((uint2*)dlo)[i] = lo.q;
  }
}

// token compaction by selected branch (runs after sel is final)
__global__ void compact_sel(const int* __restrict__ sel, int* __restrict__ idx1,
                            int* __restrict__ idx2, int* __restrict__ cnt) {
  int t = blockIdx.x * 256 + threadIdx.x;
  int s = sel[t];
  if (s == 1) idx1[atomicAdd(&cnt[0], 1)] = t;
  else if (s == 2) idx2[atomicAdd(&cnt[1], 1)] = t;
}

// pad index lists to a multiple of 128 with -1 sentinels; publish padded counts
__global__ void pad_idx(int* __restrict__ idx1, int* __restrict__ idx2,
                        const int* __restrict__ cnt, int* __restrict__ mc) {
  const int tid = threadIdx.x;
  const int n1 = cnt[0], n2 = cnt[1];
  const int p1 = (n1 + 127) & ~(int)127, p2 = (n2 + 127) & ~(int)127;
  if (tid < p1 - n1) idx1[n1 + tid] = -1;
  if (tid < p2 - n2) idx2[n2 + tid] = -1;
  if (tid == 0) { mc[0] = p1; mc[1] = p2; }
}

// ---------------------------------------------------------------------------
// bf16 GEMM body: 128x128 tile, BK=32, TRIPLE-buffered LDS (48 KB, 3 blk/CU),
// prefetch depth 2 with COUNTED vmcnt (never 0 in steady state; T4), raw
// s_barrier + counted-wait-before-barrier (each wave's own vmcnt(8) retired
// its tile-t loads -> barrier ==> whole tile resident). global_load_lds
// staging (16B/lane, linear LDS dest), 4-chunk XOR swizzle (write via
// pre-swizzled global source chunk, read via matching XOR).
// C[M,N] = A[M,K] * Bw[N,K]^T + bias
// EPI: 0 = bf16 store, 4 = fp32 scatter store to out row idx[row] (skip idx<0)
// AG:  1 = gather A rows through idx (sentinel -1 clamps to row 0)
// mcp: active row count (padded to 128); blocks past it exit.
// ---------------------------------------------------------------------------
template<int EPI, int AG>
__device__ __forceinline__
void gemm_body(const unsigned short* __restrict__ A,
               const unsigned short* __restrict__ Bw,
               const float* __restrict__ bias,
               void* __restrict__ Outv,
               const int* __restrict__ idx, const int* __restrict__ mcp,
               int N, int K) {
  __shared__ __align__(16) unsigned short As[3 * 128 * 32];
  __shared__ __align__(16) unsigned short Bs[3 * 128 * 32];
  const int tid = threadIdx.x;
  const int m0 = blockIdx.y * 128, n0 = blockIdx.x * 128;
  if (mcp && m0 >= *mcp) return;
  const int lane = tid & 63, wave = tid >> 6;
  const int wm = wave >> 1, wn = wave & 1;
  const int quad = lane >> 4, lr = lane & 15;

  // staging: round r in {0,1}; thread t covers row r*64 + (t>>2), chunk t&3
  // (16B chunks of a 64B row). LDS dest linear = t*16B; its content must be
  // global chunk (t&3) ^ (row&3).
  const int srow = tid >> 2;                   // 0..63
  const int schunk = (tid & 3) ^ (srow & 3);   // pre-swizzled source chunk
  unsigned int aoff[2], boff[2];
  #pragma unroll
  for (int r = 0; r < 2; r++) {
    int row = r * 64 + srow;
    int gr = m0 + row;
    if (AG) { int t = idx[gr]; gr = (t < 0) ? 0 : t; }
    aoff[r] = (unsigned int)gr * (unsigned int)K + (unsigned int)(schunk * 8);
    boff[r] = (unsigned int)(n0 + row) * (unsigned int)K + (unsigned int)(schunk * 8);
  }
  const int lds_dst = tid * 8;  // shorts; round r adds 2048

  f32x4 acc[4][4] = {};
  const int nk = K >> 5;  // >= 16 for all our shapes

  // stage k-tile t into buffer at short-offset `o`
  #define STAGE(T, O)                                                        \
    {                                                                        \
      const unsigned int k0 = (unsigned int)(T) << 5;                        \
      gll16(A + aoff[0] + k0, &As[(O) + lds_dst]);                           \
      gll16(A + aoff[1] + k0, &As[(O) + 2048 + lds_dst]);                    \
      gll16(Bw + boff[0] + k0, &Bs[(O) + lds_dst]);                          \
      gll16(Bw + boff[1] + k0, &Bs[(O) + 2048 + lds_dst]);                   \
    }
  // compute k-tile from buffer at short-offset `o`
  #define COMPUTE(O)                                                         \
    {                                                                        \
      short8 af[4], bfr[4];                                                  \
      _Pragma("unroll")                                                      \
      for (int i = 0; i < 4; i++) {                                          \
        const int row = wm * 64 + i * 16 + lr;                               \
        af[i] = *(const short8*)(&As[(O) + row * 32 + ((quad ^ (row & 3)) << 3)]); \
      }                                                                      \
      _Pragma("unroll")                                                      \
      for (int j = 0; j < 4; j++) {                                          \
        const int row = wn * 64 + j * 16 + lr;                               \
        bfr[j] = *(const short8*)(&Bs[(O) + row * 32 + ((quad ^ (row & 3)) << 3)]); \
      }                                                                      \
      _Pragma("unroll")                                                      \
      for (int i = 0; i < 4; i++)                                            \
        _Pragma("unroll")                                                    \
        for (int j = 0; j < 4; j++)                                          \
          acc[i][j] = __builtin_amdgcn_mfma_f32_16x16x32_bf16(af[i], bfr[j], acc[i][j], 0, 0, 0); \
    }

  int oA = 0, oB = 4096, oC = 8192;
  // prologue: tiles 0 and 1 in flight
  STAGE(0, oA);
  STAGE(1, oB);

  for (int t = 0; t < nk - 2; t++) {
    STAGE(t + 2, oC);
    asm volatile("s_waitcnt vmcnt(8)" ::: "memory");  // tile t's 4 loads done
    CFENCE; __builtin_amdgcn_s_barrier(); CFENCE;      // everyone's done
    COMPUTE(oA);
    CFENCE; __builtin_amdgcn_s_barrier(); CFENCE;      // buf oA reusable
    int tmp = oA; oA = oB; oB = oC; oC = tmp;
  }
  // t = nk-2: tile nk-1 still in flight
  asm volatile("s_waitcnt vmcnt(4)" ::: "memory");
  CFENCE; __builtin_amdgcn_s_barrier(); CFENCE;
  COMPUTE(oA);
  CFENCE; __builtin_amdgcn_s_barrier(); CFENCE;
  { int tmp = oA; oA = oB; oB = oC; oC = tmp; }
  // t = nk-1: last tile
  asm volatile("s_waitcnt vmcnt(0)" ::: "memory");
  CFENCE; __builtin_amdgcn_s_barrier(); CFENCE;
  COMPUTE(oA);
  #undef STAGE
  #undef COMPUTE

  // epilogue: C/D layout col=lane&15 (n), row=quad*4+reg (m)
  #pragma unroll
  for (int i = 0; i < 4; i++) {
    const int rbase = m0 + wm * 64 + i * 16 + quad * 4;
    #pragma unroll
    for (int j = 0; j < 4; j++) {
      const int col = n0 + wn * 64 + j * 16 + lr;
      const float bv = bias[col];
      #pragma unroll
      for (int r = 0; r < 4; r++) {
        const int row = rbase + r;
        float v = acc[i][j][r] + bv;
        if (EPI == 0) {
          ((unsigned short*)Outv)[(size_t)row * N + col] = f32_bf16(v);
        } else {  // EPI == 4
          const int tk = idx[row];
          if (tk >= 0) ((float*)Outv)[(size_t)tk * N + col] = v;
        }
      }
    }
  }
}

// named shells so rocprof shows per-stage durations
#define GEMM_SHELL(NAME, EPI, AG)                                              \
__global__ __launch_bounds__(256, 3) void NAME(                                \
    const unsigned short* __restrict__ A,                                      \
    const unsigned short* __restrict__ Bw,                                     \
    const float* __restrict__ bias, void* __restrict__ Outv,                   \
    const int* __restrict__ idx, const int* __restrict__ mcp, int N, int K) {  \
  gemm_body<EPI, AG>(A, Bw, bias, Outv, idx, mcp, N, K);                       \
}
GEMM_SHELL(g_comp1, 0, 1)
GEMM_SHELL(g_comp2, 0, 1)
GEMM_SHELL(g_adapt1, 0, 0)
GEMM_SHELL(g_adapt2, 0, 0)
GEMM_SHELL(g_dec1, 4, 0)
GEMM_SHELL(g_dec2, 4, 0)

// ---------------------------------------------------------------------------
// selector GEMM (unchanged, proven): fp32 A scaled per row-half, split hi/lo
// bf16; 3 MFMAs per fragment pair; relu + fp32 store.
// ---------------------------------------------------------------------------
__global__ __launch_bounds__(256, 2)
void gemm_sel(const float* __restrict__ Af,
              const unsigned short* __restrict__ Bw,
              const unsigned short* __restrict__ Bw2,
              const float* __restrict__ bias,
              float* __restrict__ Out,
              const float* __restrict__ scA, const float* __restrict__ scB,
              int N, int K) {
  __shared__ __align__(16) unsigned short As[2 * 128 * 32];
  __shared__ __align__(16) unsigned short Bs[2 * 128 * 32];
  const int LO = 128 * 32;
  const int tid = threadIdx.x;
  const int m0 = blockIdx.y * 128, n0 = blockIdx.x * 128;
  const int lane = tid & 63, wave = tid >> 6;
  const int wm = wave >> 1, wn = wave & 1;
  const int quad = lane >> 4, lr = lane & 15;
  const int srow = tid >> 1, scol = (tid & 1) * 16;

  const size_t aRowOff = (size_t)(m0 + srow) * K;
  const unsigned short* Brow = Bw + (size_t)(n0 + srow) * K;
  const unsigned short* Brow2 = Bw2 + (size_t)(n0 + srow) * K;

  f32x4 acc[4][4] = {};

  for (int k0 = 0; k0 < K; k0 += 32) {
    {
      const float4* src = (const float4*)(Af + aRowOff + k0 + scol);
      float4 f[4];
      f[0] = src[0]; f[1] = src[1]; f[2] = src[2]; f[3] = src[3];
      const int tk = m0 + srow;
      const float s = ((k0 + scol) * 2 < K) ? scA[tk] : scB[tk];
      union { unsigned short u[16]; uint4 q[2]; } hi;
      union { unsigned short u[16]; uint4 q[2]; } lo;
      const float* ff = (const float*)f;
      #pragma unroll
      for (int e = 0; e < 16; e++) {
        float fv = ff[e] * s;
        unsigned short hb = f32_bf16(fv);
        hi.u[e] = hb;
        lo.u[e] = f32_bf16(fv - bf16_f32(hb));
      }
      uint4* dst = (uint4*)(As + srow * 32 + scol);
      dst[0] = hi.q[0]; dst[1] = hi.q[1];
      uint4* dst2 = (uint4*)(As + LO + srow * 32 + scol);
      dst2[0] = lo.q[0]; dst2[1] = lo.q[1];
    }
    {
      const uint4* src = (const uint4*)(Brow + k0 + scol);
      uint4* dst = (uint4*)(Bs + srow * 32 + scol);
      dst[0] = src[0]; dst[1] = src[1];
      const uint4* src2 = (const uint4*)(Brow2 + k0 + scol);
      uint4* dst2 = (uint4*)(Bs + LO + srow * 32 + scol);
      dst2[0] = src2[0]; dst2[1] = src2[1];
    }
    __syncthreads();
    short8 af[4], bfr[4], af2[4], bf2[4];
    #pragma unroll
    for (int i = 0; i < 4; i++) {
      af[i]  = *(const short8*)(As + (wm * 64 + i * 16 + lr) * 32 + quad * 8);
      af2[i] = *(const short8*)(As + LO + (wm * 64 + i * 16 + lr) * 32 + quad * 8);
    }
    #pragma unroll
    for (int j = 0; j < 4; j++) {
      bfr[j] = *(const short8*)(Bs + (wn * 64 + j * 16 + lr) * 32 + quad * 8);
      bf2[j] = *(const short8*)(Bs + LO + (wn * 64 + j * 16 + lr) * 32 + quad * 8);
    }
    #pragma unroll
    for (int i = 0; i < 4; i++)
      #pragma unroll
      for (int j = 0; j < 4; j++) {
        acc[i][j] = __builtin_amdgcn_mfma_f32_16x16x32_bf16(af[i], bfr[j], acc[i][j], 0, 0, 0);
        acc[i][j] = __builtin_amdgcn_mfma_f32_16x16x32_bf16(af[i], bf2[j], acc[i][j], 0, 0, 0);
        acc[i][j] = __builtin_amdgcn_mfma_f32_16x16x32_bf16(af2[i], bfr[j], acc[i][j], 0, 0, 0);
      }
    __syncthreads();
  }

  #pragma unroll
  for (int i = 0; i < 4; i++) {
    const int rbase = m0 + wm * 64 + i * 16 + quad * 4;
    #pragma unroll
    for (int j = 0; j < 4; j++) {
      const int col = n0 + wn * 64 + j * 16 + lr;
      const float bv = bias[col];
      #pragma unroll
      for (int r = 0; r < 4; r++) {
        const int row = rbase + r;
        float v = acc[i][j][r] + bv;
        Out[(size_t)row * N + col] = fmaxf(v, 0.0f);
      }
    }
  }
}

// logits from fp32 hid, argmax + tight margin flagging. One wave per token.
__global__ __launch_bounds__(256)
void selector_logits_f32(const float* __restrict__ hidf,
                         const float* __restrict__ W2, const float* __restrict__ b2,
                         int* __restrict__ sel, int* __restrict__ risky,
                         int* __restrict__ riskyCount) {
  const int wave = threadIdx.x >> 6, lane = threadIdx.x & 63;
  const int token = blockIdx.x * 4 + wave;
  const float* hs = hidf + (size_t)token * 512 + lane * 8;
  float4 h0 = *(const float4*)hs, h1 = *(const float4*)(hs + 4);
  float p[3];
  #pragma unroll
  for (int c = 0; c < 3; c++) {
    const float* w = W2 + c * 512 + lane * 8;
    float4 w0 = *(const float4*)w, w1 = *(const float4*)(w + 4);
    p[c] = h0.x*w0.x + h0.y*w0.y + h0.z*w0.z + h0.w*w0.w
         + h1.x*w1.x + h1.y*w1.y + h1.z*w1.z + h1.w*w1.w;
  }
  #pragma unroll
  for (int off = 32; off >= 1; off >>= 1) {
    #pragma unroll
    for (int c = 0; c < 3; c++) p[c] += __shfl_xor(p[c], off, 64);
  }
  if (lane == 0) {
    float l0 = p[0] + b2[0], l1 = p[1] + b2[1], l2 = p[2] + b2[2];
    int arg = 0; float best = l0;
    if (l1 > best) { best = l1; arg = 1; }
    if (l2 > best) { best = l2; arg = 2; }
    float second;
    if (arg == 0) second = fmaxf(l1, l2);
    else if (arg == 1) second = fmaxf(l0, l2);
    else second = fmaxf(l0, l1);
    sel[token] = arg;
    if (best - second < TAU2) {
      int idx = atomicAdd(riskyCount, 1);
      risky[idx] = token;
    }
  }
}

// exact fp32 selector recompute for ultra-near-tie tokens (~100 expected).
__global__ __launch_bounds__(256)
void recheck_exact(const float* __restrict__ h, const float* __restrict__ freq,
                   const float* __restrict__ imp,
                   const float* __restrict__ W1, const float* __restrict__ b1,
                   const float* __restrict__ W2, const float* __restrict__ b2,
                   const int* __restrict__ risky, const int* __restrict__ riskyCount,
                   int* __restrict__ sel) {
  __shared__ float h_sh[2048];
  __shared__ float hid_sh[512];
  const int n = *riskyCount;
  const int tid = threadIdx.x;
  for (int ri = blockIdx.x; ri < n; ri += gridDim.x) {
    const int token = risky[ri];
    {
      const float s = (tid < 128) ? freq[token] : imp[token];
      const float4* src = (const float4*)(h + (size_t)token * 2048) + tid * 2;
      float4 v0 = src[0], v1 = src[1];
      v0.x *= s; v0.y *= s; v0.z *= s; v0.w *= s;
      v1.x *= s; v1.y *= s; v1.z *= s; v1.w *= s;
      ((float4*)h_sh)[tid * 2] = v0;
      ((float4*)h_sh)[tid * 2 + 1] = v1;
    }
    __syncthreads();
    #pragma unroll
    for (int half = 0; half < 2; half++) {
      const int o = tid + half * 256;
      const float* wrow = W1 + (size_t)o * 2048;
      float a0 = 0.f, a1 = 0.f, a2 = 0.f, a3 = 0.f;
      for (int k = 0; k < 2048; k += 16) {
        float4 w0 = *(const float4*)(wrow + k);
        float4 w1v = *(const float4*)(wrow + k + 4);
        float4 w2v = *(const float4*)(wrow + k + 8);
        float4 w3v = *(const float4*)(wrow + k + 12);
        float4 x0 = *(const float4*)(h_sh + k);
        float4 x1 = *(const float4*)(h_sh + k + 4);
        float4 x2 = *(const float4*)(h_sh + k + 8);
        float4 x3 = *(const float4*)(h_sh + k + 12);
        a0 += w0.x*x0.x + w0.y*x0.y + w0.z*x0.z + w0.w*x0.w;
        a1 += w1v.x*x1.x + w1v.y*x1.y + w1v.z*x1.z + w1v.w*x1.w;
        a2 += w2v.x*x2.x + w2v.y*x2.y + w2v.z*x2.z + w2v.w*x2.w;
        a3 += w3v.x*x3.x + w3v.y*x3.y + w3v.z*x3.z + w3v.w*x3.w;
      }
      hid_sh[o] = fmaxf((a0 + a1) + (a2 + a3) + b1[o], 0.0f);
    }
    __syncthreads();
    if (tid < 64) {
      const int lane = tid;
      const float* hs = &hid_sh[lane * 8];
      float l[3];
      #pragma unroll
      for (int c = 0; c < 3; c++) {
        const float* w = W2 + c * 512 + lane * 8;
        float s = 0.0f;
        #pragma unroll
        for (int e = 0; e < 8; e++) s += hs[e] * w[e];
        l[c] = s;
      }
      #pragma unroll
      for (int off = 32; off >= 1; off >>= 1)
        #pragma unroll
        for (int c = 0; c < 3; c++) l[c] += __shfl_xor(l[c], off, 64);
      if (lane == 0) {
        float l0 = l[0] + b2[0], l1 = l[1] + b2[1], l2 = l[2] + b2[2];
        int arg = 0; float best = l0;
        if (l1 > best) { best = l1; arg = 1; }
        if (l2 > best) { arg = 2; }
        sel[token] = arg;
      }
    }
    __syncthreads();
  }
}

__global__ __launch_bounds__(256)
void copy_sel0(const float* __restrict__ h, const int* __restrict__ sel,
               float* __restrict__ out) {
  for (int token = blockIdx.x; token < TOK; token += gridDim.x) {
    if (sel[token] != 0) continue;
    const float4* src = (const float4*)(h + (size_t)token * 2048);
    float4* dst = (float4*)(out + (size_t)token * 2048);
    dst[threadIdx.x] = src[threadIdx.x];
    dst[threadIdx.x + 256] = src[threadIdx.x + 256];
  }
}

extern "C" void kernel_launch(void* const* d_in, const int* in_sizes, int n_in,
                              void* d_out, int out_size, void* d_ws, size_t ws_size,
                              hipStream_t stream) {
  const float* h        = (const float*)d_in[0];
  const float* freq     = (const float*)d_in[1];
  const float* imp      = (const float*)d_in[2];
  const float* comp1W   = (const float*)d_in[3];
  const float* comp1b   = (const float*)d_in[4];
  const float* adapt1W  = (const float*)d_in[5];
  const float* adapt1b  = (const float*)d_in[6];
  const float* decomp1W = (const float*)d_in[7];
  const float* decomp1b = (const float*)d_in[8];
  const float* comp2W   = (const float*)d_in[9];
  const float* comp2b   = (const float*)d_in[10];
  const float* adapt2W  = (const float*)d_in[11];
  const float* adapt2b  = (const float*)d_in[12];
  const float* decomp2W = (const float*)d_in[13];
  const float* decomp2b = (const float*)d_in[14];
  const float* sel1W    = (const float*)d_in[15];
  const float* sel1b    = (const float*)d_in[16];
  const float* sel2W    = (const float*)d_in[17];
  const float* sel2b    = (const float*)d_in[18];
  float* out = (float*)d_out;

  char* ws = (char*)d_ws;
  size_t off = 0;
  auto alloc = [&](size_t bytes) -> void* {
    void* p = ws + off; off += (bytes + 255) & ~(size_t)255; return p;
  };
  unsigned short* wb_comp1   = (unsigned short*)alloc((size_t)1024 * 2048 * 2);
  unsigned short* wb_adapt1  = (unsigned short*)alloc((size_t)1024 * 1024 * 2);
  unsigned short* wb_decomp1 = (unsigned short*)alloc((size_t)2048 * 1024 * 2);
  unsigned short* wb_comp2   = (unsigned short*)alloc((size_t)512 * 2048 * 2);
  unsigned short* wb_adapt2  = (unsigned short*)alloc((size_t)512 * 512 * 2);
  unsigned short* wb_decomp2 = (unsigned short*)alloc((size_t)2048 * 512 * 2);
  unsigned short* w1hi       = (unsigned short*)alloc((size_t)512 * 2048 * 2);
  unsigned short* w1lo       = (unsigned short*)alloc((size_t)512 * 2048 * 2);
  float*          hidf       = (float*)alloc((size_t)TOK * 512 * 4);
  unsigned short* c1         = (unsigned short*)alloc((size_t)TOK * 1024 * 2);
  unsigned short* a1         = (unsigned short*)alloc((size_t)TOK * 1024 * 2);
  int* sel        = (int*)alloc((size_t)TOK * 4);
  int* risky      = (int*)alloc((size_t)TOK * 4);
  int* riskyCount = (int*)alloc(256);
  int* idx1       = (int*)alloc((size_t)TOK * 4);
  int* idx2       = (int*)alloc((size_t)TOK * 4);
  int* cnt        = (int*)alloc(256);   // [0]=n1, [1]=n2
  int* mc         = (int*)alloc(256);   // [0]=p1, [1]=p2 (padded to 128)
  // total ws: ~115 MB (proven footprint)

  // hb (bf16 h, 64 MB) lives in the FIRST HALF OF out; dead before any out
  // writes (comp1+comp2 both run before decomp/copy stages).
  unsigned short* hb = (unsigned short*)out;
  // branch-2 intermediates alias hidf (dead after selector_logits_f32)
  unsigned short* c2 = (unsigned short*)hidf;                       // 16 MB
  unsigned short* a2 = (unsigned short*)hidf + (size_t)TOK * 512;   // 16 MB

  zero3<<<1, 64, 0, stream>>>(riskyCount, cnt);

  auto cvt = [&](const float* s, unsigned short* d, int n) {
    cvt_kernel<<<(n / 4 + 255) / 256, 256, 0, stream>>>(s, d, n / 4);
  };
  cvt(comp1W,   wb_comp1,   1024 * 2048);
  cvt(adapt1W,  wb_adapt1,  1024 * 1024);
  cvt(decomp1W, wb_decomp1, 2048 * 1024);
  cvt(comp2W,   wb_comp2,   512 * 2048);
  cvt(adapt2W,  wb_adapt2,  512 * 512);
  cvt(decomp2W, wb_decomp2, 2048 * 512);
  cvt(h,        hb,         TOK * 2048);   // bf16 copy of h
  cvt_split_kernel<<<(512 * 2048 / 4 + 255) / 256, 256, 0, stream>>>(
      sel1W, w1hi, w1lo, 512 * 2048 / 4);

  // selector: hid = relu(combined @ sel1W^T + b) in split-bf16, fp32 store
  gemm_sel<<<dim3(512 / 128, TOK / 128), 256, 0, stream>>>(
      h, w1hi, w1lo, sel1b, hidf, freq, imp, 512, 2048);
  selector_logits_f32<<<TOK / 4, 256, 0, stream>>>(hidf, sel2W, sel2b, sel, risky, riskyCount);
  recheck_exact<<<256, 256, 0, stream>>>(h, freq, imp, sel1W, sel1b, sel2W, sel2b,
                                         risky, riskyCount, sel);

  // token compaction: branch GEMMs only run over their selected tokens
  compact_sel<<<TOK / 256, 256, 0, stream>>>(sel, idx1, idx2, cnt);
  pad_idx<<<1, 256, 0, stream>>>(idx1, idx2, cnt, mc);

  // both comp GEMMs first (they read hb, which lives in out)
  g_comp1<<<dim3(1024 / 128, TOK / 128), 256, 0, stream>>>(
      hb, wb_comp1, comp1b, c1, idx1, mc + 0, 1024, 2048);
  g_comp2<<<dim3(512 / 128, TOK / 128), 256, 0, stream>>>(
      hb, wb_comp2, comp2b, c2, idx2, mc + 1, 512, 2048);
  // adaptors
  g_adapt1<<<dim3(1024 / 128, TOK / 128), 256, 0, stream>>>(
      c1, wb_adapt1, adapt1b, a1, nullptr, mc + 0, 1024, 1024);
  g_adapt2<<<dim3(512 / 128, TOK / 128), 256, 0, stream>>>(
      c2, wb_adapt2, adapt2b, a2, nullptr, mc + 1, 512, 512);
  // decompressors scatter into out (hb now dead)
  g_dec1<<<dim3(2048 / 128, TOK / 128), 256, 0, stream>>>(
      a1, wb_decomp1, decomp1b, out, idx1, mc + 0, 2048, 1024);
  g_dec2<<<dim3(2048 / 128, TOK / 128), 256, 0, stream>>>(
      a2, wb_decomp2, decomp2b, out, idx2, mc + 1, 2048, 512);

  // sel==0 tokens: exact fp32 passthrough of h
  copy_sel0<<<2048, 256, 0, stream>>>(h, sel, out);
}

// Round 6
// 893.030 us; speedup vs baseline: 1.1866x; 1.0506x over previous
//
#include <hip/hip_runtime.h>
#include <hip/hip_bf16.h>

#define TOK 16384
#define TAU2 0.001f
#define CFENCE asm volatile("" ::: "memory")

typedef __attribute__((ext_vector_type(8))) short short8;
typedef __attribute__((ext_vector_type(4))) float f32x4;

__device__ __forceinline__ unsigned short f32_bf16(float f) {
  __hip_bfloat16 h = __float2bfloat16(f);
  unsigned short u;
  __builtin_memcpy(&u, &h, sizeof(u));
  return u;
}
__device__ __forceinline__ float bf16_f32(unsigned short u) {
  union { unsigned int i; float f; } c; c.i = ((unsigned int)u) << 16; return c.f;
}

// async global->LDS, 16B per lane; LDS dest linear in lane order.
__device__ __forceinline__ void gll16(const unsigned short* g, unsigned short* l) {
  __builtin_amdgcn_global_load_lds(
      (const __attribute__((address_space(1))) unsigned int*)g,
      (__attribute__((address_space(3))) unsigned int*)l, 16, 0, 0);
}

__global__ void zero3(int* a, int* c) {
  if (threadIdx.x == 0) { *a = 0; c[0] = 0; c[1] = 0; }
}

__global__ void cvt_kernel(const float* __restrict__ s, unsigned short* __restrict__ d, int n4) {
  int i = blockIdx.x * 256 + threadIdx.x;
  if (i < n4) {
    float4 v = ((const float4*)s)[i];
    union { unsigned short u[4]; uint2 q; } pk;
    pk.u[0] = f32_bf16(v.x); pk.u[1] = f32_bf16(v.y);
    pk.u[2] = f32_bf16(v.z); pk.u[3] = f32_bf16(v.w);
    ((uint2*)d)[i] = pk.q;
  }
}

// split fp32 -> (hi, lo) bf16 pair: hi = bf16(v), lo = bf16(v - f32(hi))
__global__ void cvt_split_kernel(const float* __restrict__ s,
                                 unsigned short* __restrict__ dhi,
                                 unsigned short* __restrict__ dlo, int n4) {
  int i = blockIdx.x * 256 + threadIdx.x;
  if (i < n4) {
    float4 v = ((const float4*)s)[i];
    const float* f = (const float*)&v;
    union { unsigned short u[4]; uint2 q; } hi, lo;
    #pragma unroll
    for (int e = 0; e < 4; e++) {
      unsigned short h = f32_bf16(f[e]);
      hi.u[e] = h;
      lo.u[e] = f32_bf16(f[e] - bf16_f32(h));
    }
    ((uint2*)dhi)[i] = hi.q;
    ((uint2*)dlo)[i] = lo.q;
  }
}

// token compaction by selected branch (runs after sel is final)
__global__ void compact_sel(const int* __restrict__ sel, int* __restrict__ idx1,
                            int* __restrict__ idx2, int* __restrict__ cnt) {
  int t = blockIdx.x * 256 + threadIdx.x;
  int s = sel[t];
  if (s == 1) idx1[atomicAdd(&cnt[0], 1)] = t;
  else if (s == 2) idx2[atomicAdd(&cnt[1], 1)] = t;
}

// pad index lists to a multiple of 128 with -1 sentinels; publish padded counts
__global__ void pad_idx(int* __restrict__ idx1, int* __restrict__ idx2,
                        const int* __restrict__ cnt, int* __restrict__ mc) {
  const int tid = threadIdx.x;
  const int n1 = cnt[0], n2 = cnt[1];
  const int p1 = (n1 + 127) & ~(int)127, p2 = (n2 + 127) & ~(int)127;
  if (tid < p1 - n1) idx1[n1 + tid] = -1;
  if (tid < p2 - n2) idx2[n2 + tid] = -1;
  if (tid == 0) { mc[0] = p1; mc[1] = p2; }
}

// XCD-aware decode: 1-D grid of (128 panels) x (2^LOG2NC cols). All col-tiles
// of one row-panel land on the SAME XCD (panel % 8 == xcd), so the shared A
// panel is fetched once into that XCD's L2 instead of 2^LOG2NC times from
// L3/HBM. Bijective for 128 panels (128 % 8 == 0).
#define XCD_DECODE(LOG2NC)                                                    \
  const int wgid = blockIdx.x;                                                \
  const int xcd = wgid & 7;                                                   \
  const int slot = wgid >> 3;                                                 \
  const int n0 = (slot & ((1 << (LOG2NC)) - 1)) * 128;                        \
  const int m0 = ((slot >> (LOG2NC)) * 8 + xcd) * 128;

// ---------------------------------------------------------------------------
// bf16 GEMM body: 128x128 tile, BK=32, triple-buffered LDS (48 KB, 3 blk/CU),
// prefetch depth 2 with counted vmcnt (never 0 in steady state), raw
// s_barrier + counted-wait-before-barrier. global_load_lds staging (16B/lane,
// linear LDS dest), 4-chunk XOR swizzle. XCD-aware block decode (see above).
// C[M,N] = A[M,K] * Bw[N,K]^T + bias
// EPI: 0 = bf16 store, 4 = fp32 scatter store to out row idx[row] (skip idx<0)
// AG:  1 = gather A rows through idx (sentinel -1 clamps to row 0)
// mcp: active row count (padded to 128); blocks past it exit.
// ---------------------------------------------------------------------------
template<int EPI, int AG, int LOG2NC>
__device__ __forceinline__
void gemm_body(const unsigned short* __restrict__ A,
               const unsigned short* __restrict__ Bw,
               const float* __restrict__ bias,
               void* __restrict__ Outv,
               const int* __restrict__ idx, const int* __restrict__ mcp,
               int N, int K) {
  __shared__ __align__(16) unsigned short As[3 * 128 * 32];
  __shared__ __align__(16) unsigned short Bs[3 * 128 * 32];
  const int tid = threadIdx.x;
  XCD_DECODE(LOG2NC)
  if (mcp && m0 >= *mcp) return;
  const int lane = tid & 63, wave = tid >> 6;
  const int wm = wave >> 1, wn = wave & 1;
  const int quad = lane >> 4, lr = lane & 15;

  // staging: round r in {0,1}; thread t covers row r*64 + (t>>2), chunk t&3
  // (16B chunks of a 64B row). LDS dest linear = t*16B; its content must be
  // global chunk (t&3) ^ (row&3).
  const int srow = tid >> 2;                   // 0..63
  const int schunk = (tid & 3) ^ (srow & 3);   // pre-swizzled source chunk
  unsigned int aoff[2], boff[2];
  #pragma unroll
  for (int r = 0; r < 2; r++) {
    int row = r * 64 + srow;
    int gr = m0 + row;
    if (AG) { int t = idx[gr]; gr = (t < 0) ? 0 : t; }
    aoff[r] = (unsigned int)gr * (unsigned int)K + (unsigned int)(schunk * 8);
    boff[r] = (unsigned int)(n0 + row) * (unsigned int)K + (unsigned int)(schunk * 8);
  }
  const int lds_dst = tid * 8;  // shorts; round r adds 2048

  f32x4 acc[4][4] = {};
  const int nk = K >> 5;  // >= 16 for all our shapes

  #define STAGE(T, O)                                                        \
    {                                                                        \
      const unsigned int k0 = (unsigned int)(T) << 5;                        \
      gll16(A + aoff[0] + k0, &As[(O) + lds_dst]);                           \
      gll16(A + aoff[1] + k0, &As[(O) + 2048 + lds_dst]);                    \
      gll16(Bw + boff[0] + k0, &Bs[(O) + lds_dst]);                          \
      gll16(Bw + boff[1] + k0, &Bs[(O) + 2048 + lds_dst]);                   \
    }
  #define COMPUTE(O)                                                         \
    {                                                                        \
      short8 af[4], bfr[4];                                                  \
      _Pragma("unroll")                                                      \
      for (int i = 0; i < 4; i++) {                                          \
        const int row = wm * 64 + i * 16 + lr;                               \
        af[i] = *(const short8*)(&As[(O) + row * 32 + ((quad ^ (row & 3)) << 3)]); \
      }                                                                      \
      _Pragma("unroll")                                                      \
      for (int j = 0; j < 4; j++) {                                          \
        const int row = wn * 64 + j * 16 + lr;                               \
        bfr[j] = *(const short8*)(&Bs[(O) + row * 32 + ((quad ^ (row & 3)) << 3)]); \
      }                                                                      \
      _Pragma("unroll")                                                      \
      for (int i = 0; i < 4; i++)                                            \
        _Pragma("unroll")                                                    \
        for (int j = 0; j < 4; j++)                                          \
          acc[i][j] = __builtin_amdgcn_mfma_f32_16x16x32_bf16(af[i], bfr[j], acc[i][j], 0, 0, 0); \
    }

  int oA = 0, oB = 4096, oC = 8192;
  STAGE(0, oA);
  STAGE(1, oB);

  for (int t = 0; t < nk - 2; t++) {
    STAGE(t + 2, oC);
    asm volatile("s_waitcnt vmcnt(8)" ::: "memory");  // tile t's 4 loads done
    CFENCE; __builtin_amdgcn_s_barrier(); CFENCE;
    COMPUTE(oA);
    CFENCE; __builtin_amdgcn_s_barrier(); CFENCE;
    int tmp = oA; oA = oB; oB = oC; oC = tmp;
  }
  asm volatile("s_waitcnt vmcnt(4)" ::: "memory");
  CFENCE; __builtin_amdgcn_s_barrier(); CFENCE;
  COMPUTE(oA);
  CFENCE; __builtin_amdgcn_s_barrier(); CFENCE;
  { int tmp = oA; oA = oB; oB = oC; oC = tmp; }
  asm volatile("s_waitcnt vmcnt(0)" ::: "memory");
  CFENCE; __builtin_amdgcn_s_barrier(); CFENCE;
  COMPUTE(oA);
  #undef STAGE
  #undef COMPUTE

  // epilogue: C/D layout col=lane&15 (n), row=quad*4+reg (m)
  #pragma unroll
  for (int i = 0; i < 4; i++) {
    const int rbase = m0 + wm * 64 + i * 16 + quad * 4;
    #pragma unroll
    for (int j = 0; j < 4; j++) {
      const int col = n0 + wn * 64 + j * 16 + lr;
      const float bv = bias[col];
      #pragma unroll
      for (int r = 0; r < 4; r++) {
        const int row = rbase + r;
        float v = acc[i][j][r] + bv;
        if (EPI == 0) {
          ((unsigned short*)Outv)[(size_t)row * N + col] = f32_bf16(v);
        } else {  // EPI == 4
          const int tk = idx[row];
          if (tk >= 0) ((float*)Outv)[(size_t)tk * N + col] = v;
        }
      }
    }
  }
}

// named shells so rocprof shows per-stage durations
#define GEMM_SHELL(NAME, EPI, AG, LOG2NC)                                      \
__global__ __launch_bounds__(256, 3) void NAME(                                \
    const unsigned short* __restrict__ A,                                      \
    const unsigned short* __restrict__ Bw,                                     \
    const float* __restrict__ bias, void* __restrict__ Outv,                   \
    const int* __restrict__ idx, const int* __restrict__ mcp, int N, int K) {  \
  gemm_body<EPI, AG, LOG2NC>(A, Bw, bias, Outv, idx, mcp, N, K);               \
}
GEMM_SHELL(g_comp1, 0, 1, 3)   // N=1024 -> 8 cols
GEMM_SHELL(g_comp2, 0, 1, 2)   // N=512  -> 4 cols
GEMM_SHELL(g_adapt1, 0, 0, 3)  // N=1024
GEMM_SHELL(g_adapt2, 0, 0, 2)  // N=512
GEMM_SHELL(g_dec1, 4, 0, 4)    // N=2048 -> 16 cols
GEMM_SHELL(g_dec2, 4, 0, 4)    // N=2048

// ---------------------------------------------------------------------------
// selector GEMM: fp32 A scaled per row-half, split hi/lo bf16; 3 MFMAs per
// fragment pair; relu + fp32 store. XCD-aware decode (N=512 -> LOG2NC=2).
// ---------------------------------------------------------------------------
__global__ __launch_bounds__(256, 2)
void gemm_sel(const float* __restrict__ Af,
              const unsigned short* __restrict__ Bw,
              const unsigned short* __restrict__ Bw2,
              const float* __restrict__ bias,
              float* __restrict__ Out,
              const float* __restrict__ scA, const float* __restrict__ scB,
              int N, int K) {
  __shared__ __align__(16) unsigned short As[2 * 128 * 32];
  __shared__ __align__(16) unsigned short Bs[2 * 128 * 32];
  const int LO = 128 * 32;
  const int tid = threadIdx.x;
  XCD_DECODE(2)
  const int lane = tid & 63, wave = tid >> 6;
  const int wm = wave >> 1, wn = wave & 1;
  const int quad = lane >> 4, lr = lane & 15;
  const int srow = tid >> 1, scol = (tid & 1) * 16;

  const size_t aRowOff = (size_t)(m0 + srow) * K;
  const unsigned short* Brow = Bw + (size_t)(n0 + srow) * K;
  const unsigned short* Brow2 = Bw2 + (size_t)(n0 + srow) * K;

  f32x4 acc[4][4] = {};

  for (int k0 = 0; k0 < K; k0 += 32) {
    {
      const float4* src = (const float4*)(Af + aRowOff + k0 + scol);
      float4 f[4];
      f[0] = src[0]; f[1] = src[1]; f[2] = src[2]; f[3] = src[3];
      const int tk = m0 + srow;
      const float s = ((k0 + scol) * 2 < K) ? scA[tk] : scB[tk];
      union { unsigned short u[16]; uint4 q[2]; } hi;
      union { unsigned short u[16]; uint4 q[2]; } lo;
      const float* ff = (const float*)f;
      #pragma unroll
      for (int e = 0; e < 16; e++) {
        float fv = ff[e] * s;
        unsigned short hb = f32_bf16(fv);
        hi.u[e] = hb;
        lo.u[e] = f32_bf16(fv - bf16_f32(hb));
      }
      uint4* dst = (uint4*)(As + srow * 32 + scol);
      dst[0] = hi.q[0]; dst[1] = hi.q[1];
      uint4* dst2 = (uint4*)(As + LO + srow * 32 + scol);
      dst2[0] = lo.q[0]; dst2[1] = lo.q[1];
    }
    {
      const uint4* src = (const uint4*)(Brow + k0 + scol);
      uint4* dst = (uint4*)(Bs + srow * 32 + scol);
      dst[0] = src[0]; dst[1] = src[1];
      const uint4* src2 = (const uint4*)(Brow2 + k0 + scol);
      uint4* dst2 = (uint4*)(Bs + LO + srow * 32 + scol);
      dst2[0] = src2[0]; dst2[1] = src2[1];
    }
    __syncthreads();
    short8 af[4], bfr[4], af2[4], bf2[4];
    #pragma unroll
    for (int i = 0; i < 4; i++) {
      af[i]  = *(const short8*)(As + (wm * 64 + i * 16 + lr) * 32 + quad * 8);
      af2[i] = *(const short8*)(As + LO + (wm * 64 + i * 16 + lr) * 32 + quad * 8);
    }
    #pragma unroll
    for (int j = 0; j < 4; j++) {
      bfr[j] = *(const short8*)(Bs + (wn * 64 + j * 16 + lr) * 32 + quad * 8);
      bf2[j] = *(const short8*)(Bs + LO + (wn * 64 + j * 16 + lr) * 32 + quad * 8);
    }
    #pragma unroll
    for (int i = 0; i < 4; i++)
      #pragma unroll
      for (int j = 0; j < 4; j++) {
        acc[i][j] = __builtin_amdgcn_mfma_f32_16x16x32_bf16(af[i], bfr[j], acc[i][j], 0, 0, 0);
        acc[i][j] = __builtin_amdgcn_mfma_f32_16x16x32_bf16(af[i], bf2[j], acc[i][j], 0, 0, 0);
        acc[i][j] = __builtin_amdgcn_mfma_f32_16x16x32_bf16(af2[i], bfr[j], acc[i][j], 0, 0, 0);
      }
    __syncthreads();
  }

  #pragma unroll
  for (int i = 0; i < 4; i++) {
    const int rbase = m0 + wm * 64 + i * 16 + quad * 4;
    #pragma unroll
    for (int j = 0; j < 4; j++) {
      const int col = n0 + wn * 64 + j * 16 + lr;
      const float bv = bias[col];
      #pragma unroll
      for (int r = 0; r < 4; r++) {
        const int row = rbase + r;
        float v = acc[i][j][r] + bv;
        Out[(size_t)row * N + col] = fmaxf(v, 0.0f);
      }
    }
  }
}

// logits from fp32 hid, argmax + tight margin flagging. One wave per token.
__global__ __launch_bounds__(256)
void selector_logits_f32(const float* __restrict__ hidf,
                         const float* __restrict__ W2, const float* __restrict__ b2,
                         int* __restrict__ sel, int* __restrict__ risky,
                         int* __restrict__ riskyCount) {
  const int wave = threadIdx.x >> 6, lane = threadIdx.x & 63;
  const int token = blockIdx.x * 4 + wave;
  const float* hs = hidf + (size_t)token * 512 + lane * 8;
  float4 h0 = *(const float4*)hs, h1 = *(const float4*)(hs + 4);
  float p[3];
  #pragma unroll
  for (int c = 0; c < 3; c++) {
    const float* w = W2 + c * 512 + lane * 8;
    float4 w0 = *(const float4*)w, w1 = *(const float4*)(w + 4);
    p[c] = h0.x*w0.x + h0.y*w0.y + h0.z*w0.z + h0.w*w0.w
         + h1.x*w1.x + h1.y*w1.y + h1.z*w1.z + h1.w*w1.w;
  }
  #pragma unroll
  for (int off = 32; off >= 1; off >>= 1) {
    #pragma unroll
    for (int c = 0; c < 3; c++) p[c] += __shfl_xor(p[c], off, 64);
  }
  if (lane == 0) {
    float l0 = p[0] + b2[0], l1 = p[1] + b2[1], l2 = p[2] + b2[2];
    int arg = 0; float best = l0;
    if (l1 > best) { best = l1; arg = 1; }
    if (l2 > best) { best = l2; arg = 2; }
    float second;
    if (arg == 0) second = fmaxf(l1, l2);
    else if (arg == 1) second = fmaxf(l0, l2);
    else second = fmaxf(l0, l1);
    sel[token] = arg;
    if (best - second < TAU2) {
      int idx = atomicAdd(riskyCount, 1);
      risky[idx] = token;
    }
  }
}

// exact fp32 selector recompute for ultra-near-tie tokens (~100 expected).
__global__ __launch_bounds__(256)
void recheck_exact(const float* __restrict__ h, const float* __restrict__ freq,
                   const float* __restrict__ imp,
                   const float* __restrict__ W1, const float* __restrict__ b1,
                   const float* __restrict__ W2, const float* __restrict__ b2,
                   const int* __restrict__ risky, const int* __restrict__ riskyCount,
                   int* __restrict__ sel) {
  __shared__ float h_sh[2048];
  __shared__ float hid_sh[512];
  const int n = *riskyCount;
  const int tid = threadIdx.x;
  for (int ri = blockIdx.x; ri < n; ri += gridDim.x) {
    const int token = risky[ri];
    {
      const float s = (tid < 128) ? freq[token] : imp[token];
      const float4* src = (const float4*)(h + (size_t)token * 2048) + tid * 2;
      float4 v0 = src[0], v1 = src[1];
      v0.x *= s; v0.y *= s; v0.z *= s; v0.w *= s;
      v1.x *= s; v1.y *= s; v1.z *= s; v1.w *= s;
      ((float4*)h_sh)[tid * 2] = v0;
      ((float4*)h_sh)[tid * 2 + 1] = v1;
    }
    __syncthreads();
    #pragma unroll
    for (int half = 0; half < 2; half++) {
      const int o = tid + half * 256;
      const float* wrow = W1 + (size_t)o * 2048;
      float a0 = 0.f, a1 = 0.f, a2 = 0.f, a3 = 0.f;
      for (int k = 0; k < 2048; k += 16) {
        float4 w0 = *(const float4*)(wrow + k);
        float4 w1v = *(const float4*)(wrow + k + 4);
        float4 w2v = *(const float4*)(wrow + k + 8);
        float4 w3v = *(const float4*)(wrow + k + 12);
        float4 x0 = *(const float4*)(h_sh + k);
        float4 x1 = *(const float4*)(h_sh + k + 4);
        float4 x2 = *(const float4*)(h_sh + k + 8);
        float4 x3 = *(const float4*)(h_sh + k + 12);
        a0 += w0.x*x0.x + w0.y*x0.y + w0.z*x0.z + w0.w*x0.w;
        a1 += w1v.x*x1.x + w1v.y*x1.y + w1v.z*x1.z + w1v.w*x1.w;
        a2 += w2v.x*x2.x + w2v.y*x2.y + w2v.z*x2.z + w2v.w*x2.w;
        a3 += w3v.x*x3.x + w3v.y*x3.y + w3v.z*x3.z + w3v.w*x3.w;
      }
      hid_sh[o] = fmaxf((a0 + a1) + (a2 + a3) + b1[o], 0.0f);
    }
    __syncthreads();
    if (tid < 64) {
      const int lane = tid;
      const float* hs = &hid_sh[lane * 8];
      float l[3];
      #pragma unroll
      for (int c = 0; c < 3; c++) {
        const float* w = W2 + c * 512 + lane * 8;
        float s = 0.0f;
        #pragma unroll
        for (int e = 0; e < 8; e++) s += hs[e] * w[e];
        l[c] = s;
      }
      #pragma unroll
      for (int off = 32; off >= 1; off >>= 1)
        #pragma unroll
        for (int c = 0; c < 3; c++) l[c] += __shfl_xor(l[c], off, 64);
      if (lane == 0) {
        float l0 = l[0] + b2[0], l1 = l[1] + b2[1], l2 = l[2] + b2[2];
        int arg = 0; float best = l0;
        if (l1 > best) { best = l1; arg = 1; }
        if (l2 > best) { arg = 2; }
        sel[token] = arg;
      }
    }
    __syncthreads();
  }
}

__global__ __launch_bounds__(256)
void copy_sel0(const float* __restrict__ h, const int* __restrict__ sel,
               float* __restrict__ out) {
  for (int token = blockIdx.x; token < TOK; token += gridDim.x) {
    if (sel[token] != 0) continue;
    const float4* src = (const float4*)(h + (size_t)token * 2048);
    float4* dst = (float4*)(out + (size_t)token * 2048);
    dst[threadIdx.x] = src[threadIdx.x];
    dst[threadIdx.x + 256] = src[threadIdx.x + 256];
  }
}

extern "C" void kernel_launch(void* const* d_in, const int* in_sizes, int n_in,
                              void* d_out, int out_size, void* d_ws, size_t ws_size,
                              hipStream_t stream) {
  const float* h        = (const float*)d_in[0];
  const float* freq     = (const float*)d_in[1];
  const float* imp      = (const float*)d_in[2];
  const float* comp1W   = (const float*)d_in[3];
  const float* comp1b   = (const float*)d_in[4];
  const float* adapt1W  = (const float*)d_in[5];
  const float* adapt1b  = (const float*)d_in[6];
  const float* decomp1W = (const float*)d_in[7];
  const float* decomp1b = (const float*)d_in[8];
  const float* comp2W   = (const float*)d_in[9];
  const float* comp2b   = (const float*)d_in[10];
  const float* adapt2W  = (const float*)d_in[11];
  const float* adapt2b  = (const float*)d_in[12];
  const float* decomp2W = (const float*)d_in[13];
  const float* decomp2b = (const float*)d_in[14];
  const float* sel1W    = (const float*)d_in[15];
  const float* sel1b    = (const float*)d_in[16];
  const float* sel2W    = (const float*)d_in[17];
  const float* sel2b    = (const float*)d_in[18];
  float* out = (float*)d_out;

  char* ws = (char*)d_ws;
  size_t off = 0;
  auto alloc = [&](size_t bytes) -> void* {
    void* p = ws + off; off += (bytes + 255) & ~(size_t)255; return p;
  };
  unsigned short* wb_comp1   = (unsigned short*)alloc((size_t)1024 * 2048 * 2);
  unsigned short* wb_adapt1  = (unsigned short*)alloc((size_t)1024 * 1024 * 2);
  unsigned short* wb_decomp1 = (unsigned short*)alloc((size_t)2048 * 1024 * 2);
  unsigned short* wb_comp2   = (unsigned short*)alloc((size_t)512 * 2048 * 2);
  unsigned short* wb_adapt2  = (unsigned short*)alloc((size_t)512 * 512 * 2);
  unsigned short* wb_decomp2 = (unsigned short*)alloc((size_t)2048 * 512 * 2);
  unsigned short* w1hi       = (unsigned short*)alloc((size_t)512 * 2048 * 2);
  unsigned short* w1lo       = (unsigned short*)alloc((size_t)512 * 2048 * 2);
  float*          hidf       = (float*)alloc((size_t)TOK * 512 * 4);
  unsigned short* c1         = (unsigned short*)alloc((size_t)TOK * 1024 * 2);
  unsigned short* a1         = (unsigned short*)alloc((size_t)TOK * 1024 * 2);
  int* sel        = (int*)alloc((size_t)TOK * 4);
  int* risky      = (int*)alloc((size_t)TOK * 4);
  int* riskyCount = (int*)alloc(256);
  int* idx1       = (int*)alloc((size_t)TOK * 4);
  int* idx2       = (int*)alloc((size_t)TOK * 4);
  int* cnt        = (int*)alloc(256);   // [0]=n1, [1]=n2
  int* mc         = (int*)alloc(256);   // [0]=p1, [1]=p2 (padded to 128)
  // total ws: ~115 MB (proven footprint)

  // hb (bf16 h, 64 MB) lives in the FIRST HALF OF out; dead before any out
  // writes (comp1+comp2 both run before decomp/copy stages).
  unsigned short* hb = (unsigned short*)out;
  // branch-2 intermediates alias hidf (dead after selector_logits_f32)
  unsigned short* c2 = (unsigned short*)hidf;                       // 16 MB
  unsigned short* a2 = (unsigned short*)hidf + (size_t)TOK * 512;   // 16 MB

  zero3<<<1, 64, 0, stream>>>(riskyCount, cnt);

  auto cvt = [&](const float* s, unsigned short* d, int n) {
    cvt_kernel<<<(n / 4 + 255) / 256, 256, 0, stream>>>(s, d, n / 4);
  };
  cvt(comp1W,   wb_comp1,   1024 * 2048);
  cvt(adapt1W,  wb_adapt1,  1024 * 1024);
  cvt(decomp1W, wb_decomp1, 2048 * 1024);
  cvt(comp2W,   wb_comp2,   512 * 2048);
  cvt(adapt2W,  wb_adapt2,  512 * 512);
  cvt(decomp2W, wb_decomp2, 2048 * 512);
  cvt(h,        hb,         TOK * 2048);   // bf16 copy of h
  cvt_split_kernel<<<(512 * 2048 / 4 + 255) / 256, 256, 0, stream>>>(
      sel1W, w1hi, w1lo, 512 * 2048 / 4);

  // selector: hid = relu(combined @ sel1W^T + b) in split-bf16, fp32 store
  gemm_sel<<<4 * 128, 256, 0, stream>>>(
      h, w1hi, w1lo, sel1b, hidf, freq, imp, 512, 2048);
  selector_logits_f32<<<TOK / 4, 256, 0, stream>>>(hidf, sel2W, sel2b, sel, risky, riskyCount);
  recheck_exact<<<256, 256, 0, stream>>>(h, freq, imp, sel1W, sel1b, sel2W, sel2b,
                                         risky, riskyCount, sel);

  // token compaction: branch GEMMs only run over their selected tokens
  compact_sel<<<TOK / 256, 256, 0, stream>>>(sel, idx1, idx2, cnt);
  pad_idx<<<1, 256, 0, stream>>>(idx1, idx2, cnt, mc);

  // both comp GEMMs first (they read hb, which lives in out)
  g_comp1<<<8 * 128, 256, 0, stream>>>(
      hb, wb_comp1, comp1b, c1, idx1, mc + 0, 1024, 2048);
  g_comp2<<<4 * 128, 256, 0, stream>>>(
      hb, wb_comp2, comp2b, c2, idx2, mc + 1, 512, 2048);
  // adaptors
  g_adapt1<<<8 * 128, 256, 0, stream>>>(
      c1, wb_adapt1, adapt1b, a1, nullptr, mc + 0, 1024, 1024);
  g_adapt2<<<4 * 128, 256, 0, stream>>>(
      c2, wb_adapt2, adapt2b, a2, nullptr, mc + 1, 512, 512);
  // decompressors scatter into out (hb now dead)
  g_dec1<<<16 * 128, 256, 0, stream>>>(
      a1, wb_decomp1, decomp1b, out, idx1, mc + 0, 2048, 1024);
  g_dec2<<<16 * 128, 256, 0, stream>>>(
      a2, wb_decomp2, decomp2b, out, idx2, mc + 1, 2048, 512);

  // sel==0 tokens: exact fp32 passthrough of h
  copy_sel0<<<2048, 256, 0, stream>>>(h, sel, out);
}